// Round 12
// baseline (622.442 us; speedup 1.0000x reference)
//
#include <hip/hip_runtime.h>
#include <math.h>

#define NB 32
#define NN 64
#define NS 9
#define NCS 32
#define NC 128
#define AVGF 49.0f
#define TILE 8192   // fp16 elems per (b,i) tile: 64 rows x 128 ch
#define NCHUNK 16

typedef __attribute__((ext_vector_type(8))) _Float16 f16x8;
typedef __attribute__((ext_vector_type(4))) _Float16 f16x4;
typedef __attribute__((ext_vector_type(4))) float f32x4;

#define MFMA(a,bb,c) c = __builtin_amdgcn_mfma_f32_16x16x32_f16(a,bb,c,0,0,0)

__device__ __forceinline__ float lrelu(float x){ return x>0.f ? x : 0.01f*x; }
// swizzled tile element address for (row j, channel c): 16B-slot XOR swizzle
__device__ __forceinline__ int tel(int j,int c){ return j*128 + (((c>>3)^(j&7))<<3) + (c&7); }

// ---------------- convert weights: W[k][c] fp32 -> [c][k] fp16 ----------------
// m 0..4: msgW0..3, wm0 | 5..12: eqW l W0/W1 | 13..48: eqW l basis 2..10
__global__ __launch_bounds__(256) void k_split(
    const float* __restrict__ m0, const float* __restrict__ m1,
    const float* __restrict__ m2, const float* __restrict__ m3,
    const float* __restrict__ m4, const float* __restrict__ e0,
    const float* __restrict__ e1, const float* __restrict__ e2,
    const float* __restrict__ e3, _Float16* __restrict__ outbuf)
{
    int m = blockIdx.y;
    const float* src;
    if (m < 5) src = (m == 0 ? m0 : m == 1 ? m1 : m == 2 ? m2 : m == 3 ? m3 : m4);
    else if (m < 13) {
        int l = (m - 5) >> 1, sub = (m - 5) & 1;
        const float* e = (l == 0 ? e0 : l == 1 ? e1 : l == 2 ? e2 : e3);
        src = e + sub * NC * NC;
    } else {
        int l = (m - 13) / 9, idx = (m - 13) % 9;
        const float* e = (l == 0 ? e0 : l == 1 ? e1 : l == 2 ? e2 : e3);
        src = e + (size_t)(2 + idx) * NC * NC;
    }
    int idx2 = blockIdx.x * 256 + threadIdx.x;
    int k = idx2 >> 7, c = idx2 & 127;
    outbuf[(size_t)m * 16384 + c * NC + k] = (_Float16)src[idx2];
}

// ---------------- prep: mask1, eq1to2 projections ----------------
__global__ __launch_bounds__(256) void k_prep(
    const float* __restrict__ scalars, const int* __restrict__ nobj,
    const float* __restrict__ w_in,
    float* __restrict__ mask1, float* __restrict__ P0,
    float* __restrict__ P1, float* __restrict__ P2,
    float* __restrict__ Ps3, float* __restrict__ Ps4)
{
    int b = blockIdx.x, tid = threadIdx.x;
    __shared__ float xs[NN][NS];
    __shared__ float ss[NS];
    int cnt = nobj[b];
    for (int idx = tid; idx < NN * NS; idx += 256) {
        int i = idx / NS, s = idx - i * NS;
        xs[i][s] = (i < cnt) ? scalars[(b * NN + i) * NS + s] : 0.0f;
    }
    if (tid < NN) mask1[b * NN + tid] = (tid < cnt) ? 1.0f : 0.0f;
    __syncthreads();
    if (tid < NS) {
        float a = 0.f;
        for (int i = 0; i < NN; ++i) a += xs[i][tid];
        ss[tid] = a / AVGF;
    }
    __syncthreads();
    for (int idx = tid; idx < NN * NCS; idx += 256) {
        int i = idx >> 5, d = idx & 31;
        float a0 = 0.f, a1 = 0.f, a2 = 0.f;
        #pragma unroll
        for (int s = 0; s < NS; ++s) {
            float x = xs[i][s];
            a0 += x * w_in[(0 * NS + s) * NCS + d];
            a1 += x * w_in[(1 * NS + s) * NCS + d];
            a2 += x * w_in[(2 * NS + s) * NCS + d];
        }
        P0[(b * NN + i) * NCS + d] = a0;
        P1[(b * NN + i) * NCS + d] = a1;
        P2[(b * NN + i) * NCS + d] = a2;
    }
    if (tid < NCS) {
        float a3 = 0.f, a4 = 0.f;
        #pragma unroll
        for (int s = 0; s < NS; ++s) {
            a3 += ss[s] * w_in[(3 * NS + s) * NCS + tid];
            a4 += ss[s] * w_in[(4 * NS + s) * NCS + tid];
        }
        Ps3[b * NCS + tid] = a3;
        Ps4[b * NCS + tid] = a4;
    }
}

// ---------------- F0 persistent: 4 tiles/block (512 blocks, 2/CU) ----------------
__global__ __launch_bounds__(512, 4) void k_f0(
    const float* __restrict__ momenta, const float* __restrict__ mask1,
    const float* __restrict__ P0, const float* __restrict__ P1,
    const float* __restrict__ P2, const float* __restrict__ Ps3,
    const float* __restrict__ Ps4, const float* __restrict__ b_in,
    const float* __restrict__ w_lin, const float* __restrict__ alpha,
    const _Float16* __restrict__ Wm, const float* __restrict__ bias,
    _Float16* __restrict__ U, float* __restrict__ rsum, float* __restrict__ diag,
    float* __restrict__ pcsum)
{
    __shared__ __align__(16) char smem[44672];
    _Float16* E   = (_Float16*)smem;                  // [0,16K)
    _Float16* Ust = E + TILE;                         // [16K,32K)
    float* mom  = (float*)(smem + 32768);             // [64][4]
    float* P1s  = mom + 256;                          // [64][32]
    float* psb  = P1s + 2048;                         // [32] Ps3+b_in
    float* wl   = psb + 32;                           // [96]
    float* al   = wl + 96;                            // [96]
    float* dots = al + 96;                            // [64]
    float* mjv  = dots + 64;                          // [64]
    float* pp0  = mjv + 64;                           // [32]
    float* pp2  = pp0 + 32;                           // [32] P2+Ps4
    float* Ls2  = pp2 + 32;                           // [2][128]
    int tid = threadIdx.x;
    int wg = blockIdx.x;
    int b = (wg & 7) * 4 + ((wg >> 3) & 3);           // xcd-affine
    int chunk = wg >> 5;                              // 0..15
    int i0 = chunk * 4;
    const int rb = b * NN;
    int w = tid >> 6, l = tid & 63, lr = l & 15, lk = l >> 4;
    int wr = w >> 2, wc = w & 3;
    int c0 = wc * 32 + lr, c1 = c0 + 16;
    // ---- once-per-block staging ----
    if (tid < 64) {
        *(float4*)&mom[tid*4] = *(const float4*)&momenta[(size_t)(rb + tid) * 4];
        mjv[tid] = mask1[rb + tid];
    }
    *(float4*)&P1s[tid*4] = *(const float4*)&P1[(size_t)rb * NCS + tid*4];
    if (tid < 32) psb[tid] = Ps3[b*NCS + tid] + b_in[tid];
    if (tid >= 64 && tid < 160) { wl[tid-64] = w_lin[tid-64]; al[tid-64] = alpha[tid-64]; }
    // W into registers
    f16x8 wmr[4][2];
    {
        const int cb = c0 * NC + lk * 8;
        #pragma unroll
        for (int kt = 0; kt < 4; ++kt)
            #pragma unroll
            for (int nt = 0; nt < 2; ++nt)
                wmr[kt][nt] = *(const f16x8*)&Wm[cb + nt*16*NC + kt*32];
    }
    float bs0 = bias[c0], bs1 = bias[c1];
    float mjc[2][4];
    #pragma unroll
    for (int mt = 0; mt < 2; ++mt)
        #pragma unroll
        for (int q = 0; q < 4; ++q)
            mjc[mt][q] = mask1[rb + (wr*2 + mt)*16 + lk*4 + q];
    float cs0[2][4], cs1[2][4];
    #pragma unroll
    for (int mt = 0; mt < 2; ++mt)
        #pragma unroll
        for (int q = 0; q < 4; ++q) { cs0[mt][q] = 0.f; cs1[mt][q] = 0.f; }

    int pj = tid >> 4, pks = tid & 15, pc0 = pks * 8;
    for (int t = 0; t < 4; ++t) {
        int i = i0 + t;
        float mi = mjv[i];
        if (tid < 64) {
            dots[tid] = mom[i*4+0]*mom[tid*4+0] - mom[i*4+1]*mom[tid*4+1]
                      - mom[i*4+2]*mom[tid*4+2] - mom[i*4+3]*mom[tid*4+3];
        } else if (tid < 96) {
            int c = tid - 64;
            pp0[c] = P0[(size_t)(rb+i)*NCS + c];
            pp2[c] = P2[(size_t)(rb+i)*NCS + c] + Ps4[b*NCS + c];
        }
        __syncthreads();   // B0
        // ---- build T0 tile -> E ----
        #pragma unroll
        for (int it = 0; it < 2; ++it) {
            int j = pj + it * 32;
            float m2 = mi * mjv[j];
            float v[8];
            if (pks < 4) {
                #pragma unroll
                for (int q = 0; q < 8; ++q) {
                    float x = pp0[pc0+q] + P1s[j*NCS + pc0+q] + psb[pc0+q];
                    if (j == i) x += pp2[pc0+q];
                    v[q] = lrelu(x) * m2;
                }
            } else {
                int c2 = pc0 - NCS;
                float dj = dots[j];
                #pragma unroll
                for (int q = 0; q < 8; ++q) {
                    float r = dj * wl[c2+q];
                    float lg = __log2f(1.0f + fabsf(r));
                    float s = al[c2+q] * 0.69314718f * lg;
                    v[q] = __uint_as_float(__float_as_uint(s) ^ (__float_as_uint(r) & 0x80000000u)) * m2;
                }
            }
            f16x8 hv;
            #pragma unroll
            for (int q = 0; q < 8; ++q) hv[q] = (_Float16)v[q];
            *(f16x8*)&E[j*128 + ((pks ^ (j & 7)) * 8)] = hv;
        }
        __syncthreads();   // B1
        // ---- msg MFMA ----
        f32x4 acc[2][2];
        acc[0][0]=(f32x4)0.f; acc[0][1]=(f32x4)0.f; acc[1][0]=(f32x4)0.f; acc[1][1]=(f32x4)0.f;
        #pragma unroll
        for (int kt = 0; kt < 4; ++kt)
            #pragma unroll
            for (int mt = 0; mt < 2; ++mt) {
                int row = (wr*2 + mt)*16 + lr;
                int slot = ((kt*4 + lk) ^ (row & 7)) * 8;
                f16x8 a = *(const f16x8*)&E[row*128 + slot];
                #pragma unroll
                for (int nt = 0; nt < 2; ++nt)
                    MFMA(a, wmr[kt][nt], acc[mt][nt]);
            }
        // ---- fragment epilogue ----
        float pr0 = 0.f, pr1 = 0.f;
        #pragma unroll
        for (int mt = 0; mt < 2; ++mt)
            #pragma unroll
            for (int q = 0; q < 4; ++q) {
                int j = (wr*2 + mt)*16 + lk*4 + q;
                float m2 = mi * mjc[mt][q];
                float v0 = lrelu(acc[mt][0][q] + bs0) * m2;
                float v1 = lrelu(acc[mt][1][q] + bs1) * m2;
                pr0 += v0; pr1 += v1;
                cs0[mt][q] += v0; cs1[mt][q] += v1;
                if (j == i) {
                    diag[(size_t)(rb+i)*NC + c0] = v0;
                    diag[(size_t)(rb+i)*NC + c1] = v1;
                }
                Ust[tel(j, c0)] = (_Float16)v0;
                Ust[tel(j, c1)] = (_Float16)v1;
            }
        pr0 += __shfl_xor(pr0, 16); pr0 += __shfl_xor(pr0, 32);
        pr1 += __shfl_xor(pr1, 16); pr1 += __shfl_xor(pr1, 32);
        if (l < 16) { Ls2[wr*128 + c0] = pr0; Ls2[wr*128 + c1] = pr1; }
        __syncthreads();   // B2
        size_t t0 = (size_t)(rb + i) * TILE;
        *(f16x8*)&U[t0 + (size_t)tid*8] = *(const f16x8*)&Ust[tid*8];
        *(f16x8*)&U[t0 + (size_t)(tid+512)*8] = *(const f16x8*)&Ust[(tid+512)*8];
        if (tid < 128)
            rsum[(size_t)(rb+i)*NC + tid] = (Ls2[tid] + Ls2[128 + tid]) / AVGF;
    }
    const size_t RN = (size_t)NB * NN * NC;
    #pragma unroll
    for (int mt = 0; mt < 2; ++mt)
        #pragma unroll
        for (int q = 0; q < 4; ++q) {
            int j = (wr*2 + mt)*16 + lk*4 + q;
            pcsum[(size_t)chunk * RN + (size_t)(rb+j)*NC + c0] = cs0[mt][q];
            pcsum[(size_t)chunk * RN + (size_t)(rb+j)*NC + c1] = cs1[mt][q];
        }
}

// ---------------- F_eq persistent: 4 tiles/block (512 blocks, 2/CU), W0/W1 in regs ----------------
template<int WOUT>
__global__ __launch_bounds__(512, 4) void k_feq(
    const _Float16* __restrict__ Uin,
    const _Float16* __restrict__ W0, const _Float16* __restrict__ W1,
    const _Float16* __restrict__ Wm, const float* __restrict__ mbias,
    const float* __restrict__ A, const float* __restrict__ Bc,
    const float* __restrict__ Dgv, const float* __restrict__ G,
    const float* __restrict__ Gd, const float* __restrict__ mask1,
    _Float16* __restrict__ Uo, float* __restrict__ rsum, float* __restrict__ diag,
    float* __restrict__ pcsum)
{
    __shared__ __align__(16) char smem[66560];
    _Float16* PA  = (_Float16*)smem;              // [0,16K)
    _Float16* PB  = (_Float16*)(smem + 16384);    // [16K,32K)
    _Float16* E   = (_Float16*)(smem + 32768);    // [32K,48K)
    _Float16* Ust = (_Float16*)(smem + 49152);    // [48K,64K)
    float* Ls2    = (float*)(smem + 65536);       // [2][128]
    int tid = threadIdx.x;
    int wg = blockIdx.x;
    int b = (wg & 7) * 4 + ((wg >> 3) & 3);       // xcd-affine
    int chunk = wg >> 5;                          // 0..15
    int i0 = chunk * 4;
    const int rb = b * NN;
    int w = tid >> 6, l = tid & 63, lr = l & 15, lk = l >> 4;
    int wr = w >> 2, wc = w & 3;
    int c0 = wc * 32 + lr, c1 = c0 + 16;
    const int cb = c0 * NC + lk * 8;

    // ---- W0/W1 into registers (Wm stays in L1/L2, loaded per tile) ----
    f16x8 w0r[4][2], w1r[4][2];
    #pragma unroll
    for (int kt = 0; kt < 4; ++kt)
        #pragma unroll
        for (int nt = 0; nt < 2; ++nt) {
            w0r[kt][nt] = *(const f16x8*)&W0[cb + nt*16*NC + kt*32];
            w1r[kt][nt] = *(const f16x8*)&W1[cb + nt*16*NC + kt*32];
        }
    // ---- i-invariant epilogue constants ----
    float G0 = G[(size_t)b*NC + c0], G1 = G[(size_t)b*NC + c1];
    float Gd0 = Gd[(size_t)b*NC + c0], Gd1 = Gd[(size_t)b*NC + c1];
    float mb0 = mbias[c0], mb1 = mbias[c1];
    float Bv0[2][4], Bv1[2][4], mjc[2][4], cs0[2][4], cs1[2][4];
    #pragma unroll
    for (int mt = 0; mt < 2; ++mt)
        #pragma unroll
        for (int q = 0; q < 4; ++q) {
            int j = (wr*2 + mt)*16 + lk*4 + q;
            Bv0[mt][q] = Bc[(size_t)(rb+j)*NC + c0];
            Bv1[mt][q] = Bc[(size_t)(rb+j)*NC + c1];
            mjc[mt][q] = mask1[rb + j];
            cs0[mt][q] = 0.f; cs1[mt][q] = 0.f;
        }

    int sj = tid >> 4, sks = tid & 15;
    // ---- prologue: stage tile i0 ----
    {
        size_t t0 = (size_t)(rb + i0) * TILE;
        int isw = i0 & 7;
        f16x8 r0 = *(const f16x8*)&Uin[t0 + (size_t)tid*8];
        f16x8 r1 = *(const f16x8*)&Uin[t0 + (size_t)(tid+512)*8];
        f16x8 r2 = *(const f16x8*)&Uin[(size_t)(rb+sj)*TILE + i0*128 + ((sks^isw)*8)];
        f16x8 r3 = *(const f16x8*)&Uin[(size_t)(rb+sj+32)*TILE + i0*128 + ((sks^isw)*8)];
        *(f16x8*)&PA[tid*8] = r0;
        *(f16x8*)&PA[(tid+512)*8] = r1;
        *(f16x8*)&PB[sj*128 + ((sks^(sj&7))*8)] = r2;
        *(f16x8*)&PB[(sj+32)*128 + ((sks^((sj+32)&7))*8)] = r3;
    }
    __syncthreads();

    for (int t = 0; t < 4; ++t) {
        int i = i0 + t;
        float mi = mask1[rb + i];
        float A0v = A[(size_t)(rb+i)*NC + c0] + G0;
        float A1v = A[(size_t)(rb+i)*NC + c1] + G1;
        float D0v = Dgv[(size_t)(rb+i)*NC + c0] + Gd0;
        float D1v = Dgv[(size_t)(rb+i)*NC + c1] + Gd1;
        // issue next-tile staging loads (written into PA/PB after B1)
        f16x8 r0, r1, r2, r3;
        if (t < 3) {
            int in_ = i + 1;
            size_t t0n = (size_t)(rb + in_) * TILE;
            int isw = in_ & 7;
            r0 = *(const f16x8*)&Uin[t0n + (size_t)tid*8];
            r1 = *(const f16x8*)&Uin[t0n + (size_t)(tid+512)*8];
            r2 = *(const f16x8*)&Uin[(size_t)(rb+sj)*TILE + in_*128 + ((sks^isw)*8)];
            r3 = *(const f16x8*)&Uin[(size_t)(rb+sj+32)*TILE + in_*128 + ((sks^isw)*8)];
        }
        // ---- eq MFMA: U@W0 + U^T@W1 ----
        f32x4 acc[2][2];
        acc[0][0]=(f32x4)0.f; acc[0][1]=(f32x4)0.f; acc[1][0]=(f32x4)0.f; acc[1][1]=(f32x4)0.f;
        #pragma unroll
        for (int kt = 0; kt < 4; ++kt)
            #pragma unroll
            for (int mt = 0; mt < 2; ++mt) {
                int row = (wr*2 + mt)*16 + lr;
                int slot = ((kt*4 + lk) ^ (row & 7)) * 8;
                f16x8 a1 = *(const f16x8*)&PA[row*128 + slot];
                f16x8 a2 = *(const f16x8*)&PB[row*128 + slot];
                #pragma unroll
                for (int nt = 0; nt < 2; ++nt) {
                    MFMA(a1, w0r[kt][nt], acc[mt][nt]);
                    MFMA(a2, w1r[kt][nt], acc[mt][nt]);
                }
            }
        // ---- broadcast epilogue -> E ----
        float m2v[2][4];
        #pragma unroll
        for (int mt = 0; mt < 2; ++mt)
            #pragma unroll
            for (int q = 0; q < 4; ++q) {
                int j = (wr*2 + mt)*16 + lk*4 + q;
                float m2 = mi * mjc[mt][q];
                m2v[mt][q] = m2;
                float v0 = acc[mt][0][q] + A0v + Bv0[mt][q];
                float v1 = acc[mt][1][q] + A1v + Bv1[mt][q];
                if (j == i) { v0 += D0v; v1 += D1v; }
                v0 = lrelu(v0) * m2;
                v1 = lrelu(v1) * m2;
                E[tel(j, c0)] = (_Float16)v0;
                E[tel(j, c1)] = (_Float16)v1;
            }
        __syncthreads();   // B1: E ready; ALL PA/PB reads done
        // stage-write next tile's panels (visible to next eq MFMA after B2)
        if (t < 3) {
            *(f16x8*)&PA[tid*8] = r0;
            *(f16x8*)&PA[(tid+512)*8] = r1;
            *(f16x8*)&PB[sj*128 + ((sks^(sj&7))*8)] = r2;
            *(f16x8*)&PB[(sj+32)*128 + ((sks^((sj+32)&7))*8)] = r3;
        }
        // ---- msg MFMA (Wm from L1/L2 per kt) ----
        acc[0][0]=(f32x4)0.f; acc[0][1]=(f32x4)0.f; acc[1][0]=(f32x4)0.f; acc[1][1]=(f32x4)0.f;
        #pragma unroll
        for (int kt = 0; kt < 4; ++kt) {
            f16x8 wm0 = *(const f16x8*)&Wm[cb + kt*32];
            f16x8 wm1 = *(const f16x8*)&Wm[cb + 16*NC + kt*32];
            #pragma unroll
            for (int mt = 0; mt < 2; ++mt) {
                int row = (wr*2 + mt)*16 + lr;
                int slot = ((kt*4 + lk) ^ (row & 7)) * 8;
                f16x8 e = *(const f16x8*)&E[row*128 + slot];
                MFMA(e, wm0, acc[mt][0]);
                MFMA(e, wm1, acc[mt][1]);
            }
        }
        // ---- msg epilogue ----
        float pr0 = 0.f, pr1 = 0.f;
        #pragma unroll
        for (int mt = 0; mt < 2; ++mt)
            #pragma unroll
            for (int q = 0; q < 4; ++q) {
                int j = (wr*2 + mt)*16 + lk*4 + q;
                float v0 = lrelu(acc[mt][0][q] + mb0) * m2v[mt][q];
                float v1 = lrelu(acc[mt][1][q] + mb1) * m2v[mt][q];
                pr0 += v0; pr1 += v1;
                if (WOUT) { cs0[mt][q] += v0; cs1[mt][q] += v1; }
                if (j == i) {
                    diag[(size_t)(rb+i)*NC + c0] = v0;
                    diag[(size_t)(rb+i)*NC + c1] = v1;
                }
                if (WOUT) {
                    Ust[tel(j, c0)] = (_Float16)v0;
                    Ust[tel(j, c1)] = (_Float16)v1;
                }
            }
        pr0 += __shfl_xor(pr0, 16); pr0 += __shfl_xor(pr0, 32);
        pr1 += __shfl_xor(pr1, 16); pr1 += __shfl_xor(pr1, 32);
        if (l < 16) { Ls2[wr*128 + c0] = pr0; Ls2[wr*128 + c1] = pr1; }
        __syncthreads();   // B2: Ust + Ls2 ready; PA/PB writes visible
        if (WOUT) {
            size_t t0 = (size_t)(rb + i) * TILE;
            *(f16x8*)&Uo[t0 + (size_t)tid*8] = *(const f16x8*)&Ust[tid*8];
            *(f16x8*)&Uo[t0 + (size_t)(tid+512)*8] = *(const f16x8*)&Ust[(tid+512)*8];
        }
        if (tid < 128)
            rsum[(size_t)(rb+i)*NC + tid] = (Ls2[tid] + Ls2[128 + tid]) / AVGF;
    }
    if (WOUT) {
        const size_t RN = (size_t)NB * NN * NC;
        #pragma unroll
        for (int mt = 0; mt < 2; ++mt)
            #pragma unroll
            for (int q = 0; q < 4; ++q) {
                int j = (wr*2 + mt)*16 + lk*4 + q;
                pcsum[(size_t)chunk * RN + (size_t)(rb+j)*NC + c0] = cs0[mt][q];
                pcsum[(size_t)chunk * RN + (size_t)(rb+j)*NC + c1] = cs1[mt][q];
            }
    }
}

// ---------------- red3 via MFMA: 128 blocks = 32b x 4 row-quarters ----------------
__global__ __launch_bounds__(512, 2) void k_red3(
    const float* __restrict__ rsum, const float* __restrict__ pcsum,
    const float* __restrict__ diag, const _Float16* __restrict__ Wt,
    const float* __restrict__ Weq, const float* __restrict__ eqb,
    const float* __restrict__ eqbd,
    float* __restrict__ A, float* __restrict__ Bc, float* __restrict__ Dgv,
    float* __restrict__ G, float* __restrict__ Gd)
{
    __shared__ __align__(16) char smem[50176];
    _Float16* Pd = (_Float16*)smem;            // [16][128] tel layout
    _Float16* Pr = Pd + 2048;
    _Float16* Pc = Pr + 2048;
    _Float16* WL = Pc + 2048;                  // [128][128] swizzled, 32KB
    float* tsp  = (float*)(smem + 45056);      // [4][128]
    float* trsp = tsp + 512;                   // [4][128]
    float* ts   = trsp + 512;                  // [128]
    float* trs  = ts + 128;                    // [128]
    int tid = threadIdx.x;
    int wg = blockIdx.x;
    int b = (wg & 7) * 4 + ((wg >> 3) & 3);    // xcd-affine
    int quarter = wg >> 5;
    int row0 = quarter * 16;
    const int rb = b * NN;
    const size_t RN = (size_t)NB * NN * NC;
    int w = tid >> 6, l = tid & 63, lr = l & 15, lk = l >> 4;
    int col = w * 16 + lr;                     // wave w owns 16 cols

    // ---- stage d/r panels ----
    {
        int s = tid & 255, prow = s >> 4, pks = s & 15;
        const float* src = (tid < 256 ? diag : rsum) + (size_t)(rb + row0 + prow) * NC + pks * 8;
        float4 f0 = *(const float4*)src, f1 = *(const float4*)(src + 4);
        float vv[8] = {f0.x,f0.y,f0.z,f0.w,f1.x,f1.y,f1.z,f1.w};
        f16x8 hv;
        #pragma unroll
        for (int q = 0; q < 8; ++q) hv[q] = (_Float16)vv[q];
        _Float16* dst = (tid < 256 ? Pd : Pr);
        *(f16x8*)&dst[prow*128 + ((pks ^ (prow & 7)) * 8)] = hv;
    }
    // ---- stage cl panel (sum 16 chunks) ----
    {
        int prow = tid >> 5, kq = tid & 31;
        size_t o = (size_t)(rb + row0 + prow) * NC + kq * 4;
        float s0 = 0, s1 = 0, s2 = 0, s3 = 0;
        #pragma unroll
        for (int ch = 0; ch < NCHUNK; ++ch) {
            float4 v = *(const float4*)&pcsum[(size_t)ch * RN + o];
            s0 += v.x; s1 += v.y; s2 += v.z; s3 += v.w;
        }
        f16x4 hv;
        hv[0] = (_Float16)(s0 / AVGF); hv[1] = (_Float16)(s1 / AVGF);
        hv[2] = (_Float16)(s2 / AVGF); hv[3] = (_Float16)(s3 / AVGF);
        *(f16x4*)&Pc[prow*128 + (((kq >> 1) ^ (prow & 7)) << 3) + (kq & 1) * 4] = hv;
    }
    // ---- quarter-0: ts/trs partials ----
    if (quarter == 0) {
        int c = tid & 127, part = tid >> 7;
        float st = 0.f, sd = 0.f;
        for (int ii = part*16; ii < part*16 + 16; ++ii) {
            st += rsum[(size_t)(rb+ii)*NC + c];
            sd += diag[(size_t)(rb+ii)*NC + c];
        }
        tsp[part*128 + c] = st;
        trsp[part*128 + c] = sd;
    }
    // ---- prefetch W matrix 0 ----
    f16x8 wreg[4];
    #pragma unroll
    for (int it = 0; it < 4; ++it) {
        int s = tid + it*512, c = s >> 4, ks = s & 15;
        wreg[it] = *(const f16x8*)&Wt[c*128 + ks*8];
    }
    __syncthreads();
    #pragma unroll
    for (int it = 0; it < 4; ++it) {
        int s = tid + it*512, c = s >> 4, ks = s & 15;
        *(f16x8*)&WL[c*128 + ((ks ^ (c & 7)) * 8)] = wreg[it];
    }
    if (quarter == 0 && tid < 256) {
        int c = tid & 127;
        float* dst = (tid < 128 ? ts : trs);
        float* src = (tid < 128 ? tsp : trsp);
        dst[c] = (src[c] + src[128+c] + src[256+c] + src[384+c]) / AVGF;
    }

    f32x4 acc3[3];
    acc3[0] = (f32x4)0.f; acc3[1] = (f32x4)0.f; acc3[2] = (f32x4)0.f;
    const int pan[9] = {0,0,0,1,1,2,2,1,2};  // basis 2..10 -> d/r/cl
    const int outp[9] = {2,0,1,0,1,0,1,2,2}; // basis 2..10 -> Dg/A/Bc
    #pragma unroll
    for (int m = 0; m < 9; ++m) {
        __syncthreads();   // WL(m) visible
        if (m < 8) {
            const _Float16* Wn = Wt + (size_t)(m+1) * 16384;
            #pragma unroll
            for (int it = 0; it < 4; ++it) {
                int s = tid + it*512, c = s >> 4, ks = s & 15;
                wreg[it] = *(const f16x8*)&Wn[c*128 + ks*8];
            }
        }
        const _Float16* P = (pan[m] == 0 ? Pd : pan[m] == 1 ? Pr : Pc);
        #pragma unroll
        for (int kt = 0; kt < 4; ++kt) {
            f16x8 a = *(const f16x8*)&P[lr*128 + (((kt*4+lk) ^ (lr & 7)) * 8)];
            f16x8 bb = *(const f16x8*)&WL[col*128 + (((kt*4+lk) ^ (lr & 7)) * 8)];
            MFMA(a, bb, acc3[outp[m]]);
        }
        __syncthreads();   // MFMA reads of WL done
        if (m < 8) {
            #pragma unroll
            for (int it = 0; it < 4; ++it) {
                int s = tid + it*512, c = s >> 4, ks = s & 15;
                *(f16x8*)&WL[c*128 + ((ks ^ (c & 7)) * 8)] = wreg[it];
            }
        }
    }
    #pragma unroll
    for (int q = 0; q < 4; ++q) {
        size_t o = (size_t)(rb + row0 + lk*4 + q) * NC + col;
        A[o]   = acc3[0][q];
        Bc[o]  = acc3[1][q];
        Dgv[o] = acc3[2][q];
    }
    if (quarter == 0) {
        __syncthreads();
        int c = tid & 127, part = tid >> 7;
        float g = 0.f, gd = 0.f;
        for (int k = part*32; k < part*32 + 32; ++k) {
            float tv = ts[k], rv = trs[k];
            g  += tv * Weq[(11*NC + k)*NC + c] + rv * Weq[(13*NC + k)*NC + c];
            gd += tv * Weq[(12*NC + k)*NC + c] + rv * Weq[(14*NC + k)*NC + c];
        }
        tsp[part*128 + c] = g;
        trsp[part*128 + c] = gd;
        __syncthreads();
        if (tid < 128) {
            float gg = eqb[tid] + tsp[tid] + tsp[128+tid] + tsp[256+tid] + tsp[384+tid];
            float gdd = eqbd[tid] + trsp[tid] + trsp[128+tid] + trsp[256+tid] + trsp[384+tid];
            G[b*NC + tid] = gg;
            Gd[b*NC + tid] = gdd;
        }
    }
}

// ---------------- Eq2to0 head + output MLP ----------------
__global__ __launch_bounds__(128) void k_final(
    const float* __restrict__ rsum, const float* __restrict__ diag,
    const float* __restrict__ w20, const float* __restrict__ b20,
    const float* __restrict__ wmlp, const float* __restrict__ bmlp,
    float* __restrict__ outp)
{
    int b = blockIdx.x;
    int c = threadIdx.x;
    __shared__ float agg0[NC], agg1[NC], act3[NC];
    float dgv = 0.f, tot = 0.f;
    for (int i = 0; i < NN; ++i) {
        dgv += diag[(size_t)(b * NN + i) * NC + c];
        tot += rsum[(size_t)(b * NN + i) * NC + c];
    }
    agg0[c] = lrelu(dgv / AVGF);
    agg1[c] = lrelu(tot / AVGF);
    __syncthreads();
    float a3 = b20[c];
    for (int k = 0; k < NC; ++k)
        a3 += agg0[k] * w20[k * NC + c] + agg1[k] * w20[(NC + k) * NC + c];
    act3[c] = a3;
    __syncthreads();
    if (c < 2) {
        float o = bmlp[c];
        for (int d = 0; d < NC; ++d) o += act3[d] * wmlp[d * 2 + c];
        outp[b * 2 + c] = o;
    }
}

extern "C" void kernel_launch(void* const* d_in, const int* in_sizes, int n_in,
                              void* d_out, int out_size, void* d_ws, size_t ws_size,
                              hipStream_t stream)
{
    const float* momenta = (const float*)d_in[0];
    const float* scalars = (const float*)d_in[1];
    const int*   nobj    = (const int*)d_in[2];
    const float* w_lin   = (const float*)d_in[3];
    const float* alpha   = (const float*)d_in[4];
    const float* w_in    = (const float*)d_in[5];
    const float* b_in    = (const float*)d_in[6];
    const float *msgW[4], *msgB[4], *eqW[4], *eqB[4], *eqBd[4];
    const float *wm0, *bm0, *w20, *b20, *wmlp, *bmlp;
    if (n_in >= 33) {
        for (int l = 0; l < 4; ++l) {
            msgW[l] = (const float*)d_in[7 + l];
            msgB[l] = (const float*)d_in[11 + l];
            eqW[l]  = (const float*)d_in[15 + l];
            eqB[l]  = (const float*)d_in[19 + l];
            eqBd[l] = (const float*)d_in[23 + l];
        }
        wm0  = (const float*)d_in[27]; bm0  = (const float*)d_in[28];
        w20  = (const float*)d_in[29]; b20  = (const float*)d_in[30];
        wmlp = (const float*)d_in[31]; bmlp = (const float*)d_in[32];
    } else {
        for (int l = 0; l < 4; ++l) {
            msgW[l] = (const float*)d_in[7] + (size_t)l * NC * NC;
            msgB[l] = (const float*)d_in[8] + l * NC;
            eqW[l]  = (const float*)d_in[9] + (size_t)l * 15 * NC * NC;
            eqB[l]  = (const float*)d_in[10] + l * NC;
            eqBd[l] = (const float*)d_in[11] + l * NC;
        }
        wm0  = (const float*)d_in[12]; bm0  = (const float*)d_in[13];
        w20  = (const float*)d_in[14]; b20  = (const float*)d_in[15];
        wmlp = (const float*)d_in[16]; bmlp = (const float*)d_in[17];
    }

    // ---- workspace layout ----
    const size_t TN2 = (size_t)NB * NN * TILE;       // fp16 elems per tile array
    const size_t RN  = (size_t)NB * NN * NC;         // floats per row-vector array
    _Float16* X  = (_Float16*)d_ws;
    _Float16* Y  = X + TN2;
    _Float16* SW = Y + TN2;                          // 49 * 16384 fp16
    float* fp = (float*)(((uintptr_t)(SW + 49 * 16384) + 15) & ~(uintptr_t)15);
    float* rsum  = fp;
    float* pcsum = rsum + RN;                        // 16 chunks
    float* diag  = pcsum + NCHUNK * RN;
    float* Aa    = diag + RN;
    float* Bb    = Aa + RN;
    float* Dgv   = Bb + RN;
    float* G     = Dgv + RN;
    float* Gd    = G + NB * NC;
    float* mask1 = Gd + NB * NC;
    float* P0    = mask1 + NB * NN;
    float* P1    = P0 + (size_t)NB * NN * NCS;
    float* P2    = P1 + (size_t)NB * NN * NCS;
    float* Ps3   = P2 + (size_t)NB * NN * NCS;
    float* Ps4   = Ps3 + NB * NCS;
    size_t need = (size_t)((char*)(Ps4 + NB * NCS) - (char*)d_ws);
    if (ws_size < need) return;

    k_split<<<dim3(64, 49), 256, 0, stream>>>(msgW[0], msgW[1], msgW[2], msgW[3],
                                              wm0, eqW[0], eqW[1], eqW[2], eqW[3], SW);
    k_prep<<<NB, 256, 0, stream>>>(scalars, nobj, w_in, mask1, P0, P1, P2, Ps3, Ps4);

    k_f0<<<512, 512, 0, stream>>>(momenta, mask1, P0, P1, P2, Ps3, Ps4,
                                  b_in, w_lin, alpha, SW /*msgW[0]*/,
                                  msgB[0], X, rsum, diag, pcsum);

    _Float16 *in = X, *out = Y;
    for (int l = 0; l < 4; ++l) {
        _Float16* Wt = SW + (size_t)(13 + l * 9) * 16384;
        k_red3<<<128, 512, 0, stream>>>(rsum, pcsum, diag, Wt, eqW[l],
                                        eqB[l], eqBd[l], Aa, Bb, Dgv, G, Gd);
        _Float16* W0 = SW + (size_t)(5 + 2 * l) * 16384;
        _Float16* W1 = W0 + 16384;
        if (l < 3) {
            _Float16* Wm = SW + (size_t)(l + 1) * 16384;
            k_feq<1><<<512, 512, 0, stream>>>(in, W0, W1, Wm, msgB[l + 1],
                                              Aa, Bb, Dgv, G, Gd, mask1,
                                              out, rsum, diag, pcsum);
            _Float16* t = in; in = out; out = t;
        } else {
            _Float16* Wm = SW + (size_t)4 * 16384;    // wm0
            k_feq<0><<<512, 512, 0, stream>>>(in, W0, W1, Wm, bm0,
                                              Aa, Bb, Dgv, G, Gd, mask1,
                                              out, rsum, diag, pcsum);
        }
    }
    k_final<<<NB, 128, 0, stream>>>(rsum, diag, w20, b20, wmlp, bmlp, (float*)d_out);
}

// Round 13
// 450.613 us; speedup vs baseline: 1.3813x; 1.3813x over previous
//
#include <hip/hip_runtime.h>
#include <math.h>

#define NB 32
#define NN 64
#define NS 9
#define NCS 32
#define NC 128
#define AVGF 49.0f
#define TILE 8192   // fp16 elems per (b,i) tile: 64 rows x 128 ch

typedef __attribute__((ext_vector_type(8))) _Float16 f16x8;
typedef __attribute__((ext_vector_type(4))) _Float16 f16x4;
typedef __attribute__((ext_vector_type(4))) float f32x4;

#define MFMA(a,bb,c) c = __builtin_amdgcn_mfma_f32_16x16x32_f16(a,bb,c,0,0,0)

__device__ __forceinline__ float lrelu(float x){ return x>0.f ? x : 0.01f*x; }
// swizzled tile element address for (row j, channel c): 16B-slot XOR swizzle
__device__ __forceinline__ int tel(int j,int c){ return j*128 + (((c>>3)^(j&7))<<3) + (c&7); }

// ---------------- convert weights: W[k][c] fp32 -> [c][k] fp16 ----------------
// m 0..4: msgW0..3, wm0 | 5..12: eqW l W0/W1 | 13..48: eqW l basis 2..10
__global__ __launch_bounds__(256) void k_split(
    const float* __restrict__ m0, const float* __restrict__ m1,
    const float* __restrict__ m2, const float* __restrict__ m3,
    const float* __restrict__ m4, const float* __restrict__ e0,
    const float* __restrict__ e1, const float* __restrict__ e2,
    const float* __restrict__ e3, _Float16* __restrict__ outbuf)
{
    int m = blockIdx.y;
    const float* src;
    if (m < 5) src = (m == 0 ? m0 : m == 1 ? m1 : m == 2 ? m2 : m == 3 ? m3 : m4);
    else if (m < 13) {
        int l = (m - 5) >> 1, sub = (m - 5) & 1;
        const float* e = (l == 0 ? e0 : l == 1 ? e1 : l == 2 ? e2 : e3);
        src = e + sub * NC * NC;
    } else {
        int l = (m - 13) / 9, idx = (m - 13) % 9;
        const float* e = (l == 0 ? e0 : l == 1 ? e1 : l == 2 ? e2 : e3);
        src = e + (size_t)(2 + idx) * NC * NC;
    }
    int idx2 = blockIdx.x * 256 + threadIdx.x;
    int k = idx2 >> 7, c = idx2 & 127;
    outbuf[(size_t)m * 16384 + c * NC + k] = (_Float16)src[idx2];
}

// ---------------- prep: mask1, eq1to2 projections ----------------
__global__ __launch_bounds__(256) void k_prep(
    const float* __restrict__ scalars, const int* __restrict__ nobj,
    const float* __restrict__ w_in,
    float* __restrict__ mask1, float* __restrict__ P0,
    float* __restrict__ P1, float* __restrict__ P2,
    float* __restrict__ Ps3, float* __restrict__ Ps4)
{
    int b = blockIdx.x, tid = threadIdx.x;
    __shared__ float xs[NN][NS];
    __shared__ float ss[NS];
    int cnt = nobj[b];
    for (int idx = tid; idx < NN * NS; idx += 256) {
        int i = idx / NS, s = idx - i * NS;
        xs[i][s] = (i < cnt) ? scalars[(b * NN + i) * NS + s] : 0.0f;
    }
    if (tid < NN) mask1[b * NN + tid] = (tid < cnt) ? 1.0f : 0.0f;
    __syncthreads();
    if (tid < NS) {
        float a = 0.f;
        for (int i = 0; i < NN; ++i) a += xs[i][tid];
        ss[tid] = a / AVGF;
    }
    __syncthreads();
    for (int idx = tid; idx < NN * NCS; idx += 256) {
        int i = idx >> 5, d = idx & 31;
        float a0 = 0.f, a1 = 0.f, a2 = 0.f;
        #pragma unroll
        for (int s = 0; s < NS; ++s) {
            float x = xs[i][s];
            a0 += x * w_in[(0 * NS + s) * NCS + d];
            a1 += x * w_in[(1 * NS + s) * NCS + d];
            a2 += x * w_in[(2 * NS + s) * NCS + d];
        }
        P0[(b * NN + i) * NCS + d] = a0;
        P1[(b * NN + i) * NCS + d] = a1;
        P2[(b * NN + i) * NCS + d] = a2;
    }
    if (tid < NCS) {
        float a3 = 0.f, a4 = 0.f;
        #pragma unroll
        for (int s = 0; s < NS; ++s) {
            a3 += ss[s] * w_in[(3 * NS + s) * NCS + tid];
            a4 += ss[s] * w_in[(4 * NS + s) * NCS + tid];
        }
        Ps3[b * NCS + tid] = a3;
        Ps4[b * NCS + tid] = a4;
    }
}

// ---------------- F0 persistent: 8 tiles/block; build T0 in LDS, msg1 MFMA, csum-fold ----------------
__global__ __launch_bounds__(512, 2) void k_f0(
    const float* __restrict__ momenta, const float* __restrict__ mask1,
    const float* __restrict__ P0, const float* __restrict__ P1,
    const float* __restrict__ P2, const float* __restrict__ Ps3,
    const float* __restrict__ Ps4, const float* __restrict__ b_in,
    const float* __restrict__ w_lin, const float* __restrict__ alpha,
    const _Float16* __restrict__ Wm, const float* __restrict__ bias,
    _Float16* __restrict__ U, float* __restrict__ rsum, float* __restrict__ diag,
    float* __restrict__ pcsum)
{
    __shared__ __align__(16) char smem[44672];
    _Float16* E   = (_Float16*)smem;                  // [0,16K)
    _Float16* Ust = E + TILE;                         // [16K,32K)
    float* mom  = (float*)(smem + 32768);             // [64][4]
    float* P1s  = mom + 256;                          // [64][32]
    float* psb  = P1s + 2048;                         // [32] Ps3+b_in
    float* wl   = psb + 32;                           // [96]
    float* al   = wl + 96;                            // [96]
    float* dots = al + 96;                            // [64]
    float* mjv  = dots + 64;                          // [64]
    float* pp0  = mjv + 64;                           // [32]
    float* pp2  = pp0 + 32;                           // [32] P2+Ps4
    float* Ls2  = pp2 + 32;                           // [2][128]
    int tid = threadIdx.x;
    int wg = blockIdx.x;
    int b = (wg & 7) * 4 + ((wg >> 3) & 3);           // xcd-affine
    int i0 = (wg >> 5) * 8;
    int chunk = wg >> 5;
    const int rb = b * NN;
    int w = tid >> 6, l = tid & 63, lr = l & 15, lk = l >> 4;
    int wr = w >> 2, wc = w & 3;
    int c0 = wc * 32 + lr, c1 = c0 + 16;
    // ---- once-per-block staging ----
    if (tid < 64) {
        *(float4*)&mom[tid*4] = *(const float4*)&momenta[(size_t)(rb + tid) * 4];
        mjv[tid] = mask1[rb + tid];
    }
    *(float4*)&P1s[tid*4] = *(const float4*)&P1[(size_t)rb * NCS + tid*4];
    if (tid < 32) psb[tid] = Ps3[b*NCS + tid] + b_in[tid];
    if (tid >= 64 && tid < 160) { wl[tid-64] = w_lin[tid-64]; al[tid-64] = alpha[tid-64]; }
    // W into registers
    f16x8 wmr[4][2];
    {
        const int cb = c0 * NC + lk * 8;
        #pragma unroll
        for (int kt = 0; kt < 4; ++kt)
            #pragma unroll
            for (int nt = 0; nt < 2; ++nt)
                wmr[kt][nt] = *(const f16x8*)&Wm[cb + nt*16*NC + kt*32];
    }
    float bs0 = bias[c0], bs1 = bias[c1];
    float mjc[2][4];
    #pragma unroll
    for (int mt = 0; mt < 2; ++mt)
        #pragma unroll
        for (int q = 0; q < 4; ++q)
            mjc[mt][q] = mask1[rb + (wr*2 + mt)*16 + lk*4 + q];
    float cs0[2][4], cs1[2][4];
    #pragma unroll
    for (int mt = 0; mt < 2; ++mt)
        #pragma unroll
        for (int q = 0; q < 4; ++q) { cs0[mt][q] = 0.f; cs1[mt][q] = 0.f; }

    int pj = tid >> 4, pks = tid & 15, pc0 = pks * 8;
    for (int t = 0; t < 8; ++t) {
        int i = i0 + t;
        float mi = mjv[i];
        if (tid < 64) {
            dots[tid] = mom[i*4+0]*mom[tid*4+0] - mom[i*4+1]*mom[tid*4+1]
                      - mom[i*4+2]*mom[tid*4+2] - mom[i*4+3]*mom[tid*4+3];
        } else if (tid < 96) {
            int c = tid - 64;
            pp0[c] = P0[(size_t)(rb+i)*NCS + c];
            pp2[c] = P2[(size_t)(rb+i)*NCS + c] + Ps4[b*NCS + c];
        }
        __syncthreads();   // B0
        // ---- build T0 tile -> E ----
        #pragma unroll
        for (int it = 0; it < 2; ++it) {
            int j = pj + it * 32;
            float m2 = mi * mjv[j];
            float v[8];
            if (pks < 4) {
                #pragma unroll
                for (int q = 0; q < 8; ++q) {
                    float x = pp0[pc0+q] + P1s[j*NCS + pc0+q] + psb[pc0+q];
                    if (j == i) x += pp2[pc0+q];
                    v[q] = lrelu(x) * m2;
                }
            } else {
                int c2 = pc0 - NCS;
                float dj = dots[j];
                #pragma unroll
                for (int q = 0; q < 8; ++q) {
                    float r = dj * wl[c2+q];
                    float lg = __log2f(1.0f + fabsf(r));
                    float s = al[c2+q] * 0.69314718f * lg;
                    v[q] = __uint_as_float(__float_as_uint(s) ^ (__float_as_uint(r) & 0x80000000u)) * m2;
                }
            }
            f16x8 hv;
            #pragma unroll
            for (int q = 0; q < 8; ++q) hv[q] = (_Float16)v[q];
            *(f16x8*)&E[j*128 + ((pks ^ (j & 7)) * 8)] = hv;
        }
        __syncthreads();   // B1
        // ---- msg MFMA ----
        f32x4 acc[2][2];
        acc[0][0]=(f32x4)0.f; acc[0][1]=(f32x4)0.f; acc[1][0]=(f32x4)0.f; acc[1][1]=(f32x4)0.f;
        #pragma unroll
        for (int kt = 0; kt < 4; ++kt)
            #pragma unroll
            for (int mt = 0; mt < 2; ++mt) {
                int row = (wr*2 + mt)*16 + lr;
                int slot = ((kt*4 + lk) ^ (row & 7)) * 8;
                f16x8 a = *(const f16x8*)&E[row*128 + slot];
                #pragma unroll
                for (int nt = 0; nt < 2; ++nt)
                    MFMA(a, wmr[kt][nt], acc[mt][nt]);
            }
        // ---- fragment epilogue ----
        float pr0 = 0.f, pr1 = 0.f;
        #pragma unroll
        for (int mt = 0; mt < 2; ++mt)
            #pragma unroll
            for (int q = 0; q < 4; ++q) {
                int j = (wr*2 + mt)*16 + lk*4 + q;
                float m2 = mi * mjc[mt][q];
                float v0 = lrelu(acc[mt][0][q] + bs0) * m2;
                float v1 = lrelu(acc[mt][1][q] + bs1) * m2;
                pr0 += v0; pr1 += v1;
                cs0[mt][q] += v0; cs1[mt][q] += v1;
                if (j == i) {
                    diag[(size_t)(rb+i)*NC + c0] = v0;
                    diag[(size_t)(rb+i)*NC + c1] = v1;
                }
                Ust[tel(j, c0)] = (_Float16)v0;
                Ust[tel(j, c1)] = (_Float16)v1;
            }
        pr0 += __shfl_xor(pr0, 16); pr0 += __shfl_xor(pr0, 32);
        pr1 += __shfl_xor(pr1, 16); pr1 += __shfl_xor(pr1, 32);
        if (l < 16) { Ls2[wr*128 + c0] = pr0; Ls2[wr*128 + c1] = pr1; }
        __syncthreads();   // B2
        size_t t0 = (size_t)(rb + i) * TILE;
        *(f16x8*)&U[t0 + (size_t)tid*8] = *(const f16x8*)&Ust[tid*8];
        *(f16x8*)&U[t0 + (size_t)(tid+512)*8] = *(const f16x8*)&Ust[(tid+512)*8];
        if (tid < 128)
            rsum[(size_t)(rb+i)*NC + tid] = (Ls2[tid] + Ls2[128 + tid]) / AVGF;
    }
    const size_t RN = (size_t)NB * NN * NC;
    #pragma unroll
    for (int mt = 0; mt < 2; ++mt)
        #pragma unroll
        for (int q = 0; q < 4; ++q) {
            int j = (wr*2 + mt)*16 + lk*4 + q;
            pcsum[(size_t)chunk * RN + (size_t)(rb+j)*NC + c0] = cs0[mt][q];
            pcsum[(size_t)chunk * RN + (size_t)(rb+j)*NC + c1] = cs1[mt][q];
        }
}

// ---------------- F_eq persistent: 1024 threads (16 waves), 8 tiles/block, W0/W1 in regs, Wm in LDS ----------------
template<int WOUT>
__global__ __launch_bounds__(1024, 4) void k_feq(
    const _Float16* __restrict__ Uin,
    const _Float16* __restrict__ W0, const _Float16* __restrict__ W1,
    const _Float16* __restrict__ Wm, const float* __restrict__ mbias,
    const float* __restrict__ A, const float* __restrict__ Bc,
    const float* __restrict__ Dgv, const float* __restrict__ G,
    const float* __restrict__ Gd, const float* __restrict__ mask1,
    _Float16* __restrict__ Uo, float* __restrict__ rsum, float* __restrict__ diag,
    float* __restrict__ pcsum)
{
    __shared__ __align__(16) char smem[100352];
    _Float16* PA  = (_Float16*)smem;              // [0,16K)
    _Float16* PB  = (_Float16*)(smem + 16384);    // [16K,32K)
    _Float16* E   = (_Float16*)(smem + 32768);    // [32K,48K)
    _Float16* Ust = (_Float16*)(smem + 49152);    // [48K,64K)
    _Float16* WmL = (_Float16*)(smem + 65536);    // [64K,96K) swizzled Wm
    float* Ls2    = (float*)(smem + 98304);       // [4][128]
    int tid = threadIdx.x;
    int wg = blockIdx.x;
    int b = (wg & 7) * 4 + ((wg >> 3) & 3);       // xcd-affine
    int chunk = wg >> 5;                          // 0..7
    int i0 = chunk * 8;
    const int rb = b * NN;
    int w = tid >> 6, l = tid & 63, lr = l & 15, lk = l >> 4;
    int wr = w >> 2, wc = w & 3;                  // 4x4 wave grid
    int c0 = wc * 32 + lr, c1 = c0 + 16;
    const int cb = c0 * NC + lk * 8;

    // ---- W0/W1 into registers (64 VGPRs, held for whole kernel) ----
    f16x8 w0r[4][2], w1r[4][2];
    #pragma unroll
    for (int kt = 0; kt < 4; ++kt)
        #pragma unroll
        for (int nt = 0; nt < 2; ++nt) {
            w0r[kt][nt] = *(const f16x8*)&W0[cb + nt*16*NC + kt*32];
            w1r[kt][nt] = *(const f16x8*)&W1[cb + nt*16*NC + kt*32];
        }
    // ---- stage Wm into LDS (swizzled like red3's WL; verified pattern) ----
    #pragma unroll
    for (int it = 0; it < 2; ++it) {
        int s = tid + it * 1024, c = s >> 4, ks = s & 15;
        *(f16x8*)&WmL[c*128 + ((ks ^ (c & 7)) * 8)] = *(const f16x8*)&Wm[c*128 + ks*8];
    }
    // ---- i-invariant epilogue constants ----
    float G0 = G[(size_t)b*NC + c0], G1 = G[(size_t)b*NC + c1];
    float Gd0 = Gd[(size_t)b*NC + c0], Gd1 = Gd[(size_t)b*NC + c1];
    float mb0 = mbias[c0], mb1 = mbias[c1];
    float Bv0[4], Bv1[4], mjc[4], cs0[4], cs1[4];
    #pragma unroll
    for (int q = 0; q < 4; ++q) {
        int j = wr*16 + lk*4 + q;
        Bv0[q] = Bc[(size_t)(rb+j)*NC + c0];
        Bv1[q] = Bc[(size_t)(rb+j)*NC + c1];
        mjc[q] = mask1[rb + j];
        cs0[q] = 0.f; cs1[q] = 0.f;
    }

    int sj = tid >> 4, sks = tid & 15;
    // ---- prologue: stage tile i0 (1 row-chunk + 1 col-chunk per thread) ----
    {
        size_t t0 = (size_t)(rb + i0) * TILE;
        int isw = i0 & 7;
        f16x8 r0 = *(const f16x8*)&Uin[t0 + (size_t)tid*8];
        f16x8 r1 = *(const f16x8*)&Uin[(size_t)(rb+sj)*TILE + i0*128 + ((sks^isw)*8)];
        *(f16x8*)&PA[tid*8] = r0;
        *(f16x8*)&PB[sj*128 + ((sks^(sj&7))*8)] = r1;
    }
    __syncthreads();

    for (int t = 0; t < 8; ++t) {
        int i = i0 + t;
        float mi = mask1[rb + i];
        float A0v = A[(size_t)(rb+i)*NC + c0] + G0;
        float A1v = A[(size_t)(rb+i)*NC + c1] + G1;
        float D0v = Dgv[(size_t)(rb+i)*NC + c0] + Gd0;
        float D1v = Dgv[(size_t)(rb+i)*NC + c1] + Gd1;
        // issue next-tile staging loads (written into PA/PB after B1)
        f16x8 r0, r1;
        if (t < 7) {
            int in_ = i + 1;
            size_t t0n = (size_t)(rb + in_) * TILE;
            int isw = in_ & 7;
            r0 = *(const f16x8*)&Uin[t0n + (size_t)tid*8];
            r1 = *(const f16x8*)&Uin[(size_t)(rb+sj)*TILE + in_*128 + ((sks^isw)*8)];
        }
        // ---- eq MFMA: U@W0 + U^T@W1 (wave owns rows wr*16..+15, cols wc*32..+31) ----
        f32x4 acc[2];
        acc[0] = (f32x4)0.f; acc[1] = (f32x4)0.f;
        #pragma unroll
        for (int kt = 0; kt < 4; ++kt) {
            int row = wr*16 + lr;
            int slot = ((kt*4 + lk) ^ (row & 7)) * 8;
            f16x8 a1 = *(const f16x8*)&PA[row*128 + slot];
            f16x8 a2 = *(const f16x8*)&PB[row*128 + slot];
            #pragma unroll
            for (int nt = 0; nt < 2; ++nt) {
                MFMA(a1, w0r[kt][nt], acc[nt]);
                MFMA(a2, w1r[kt][nt], acc[nt]);
            }
        }
        // ---- broadcast epilogue -> E ----
        float m2v[4];
        #pragma unroll
        for (int q = 0; q < 4; ++q) {
            int j = wr*16 + lk*4 + q;
            float m2 = mi * mjc[q];
            m2v[q] = m2;
            float v0 = acc[0][q] + A0v + Bv0[q];
            float v1 = acc[1][q] + A1v + Bv1[q];
            if (j == i) { v0 += D0v; v1 += D1v; }
            v0 = lrelu(v0) * m2;
            v1 = lrelu(v1) * m2;
            E[tel(j, c0)] = (_Float16)v0;
            E[tel(j, c1)] = (_Float16)v1;
        }
        __syncthreads();   // B1: E ready; ALL PA/PB reads done
        // stage-write next tile's panels (visible after B2)
        if (t < 7) {
            *(f16x8*)&PA[tid*8] = r0;
            *(f16x8*)&PB[sj*128 + ((sks^(sj&7))*8)] = r1;
        }
        // ---- msg MFMA (Wm from LDS) ----
        acc[0] = (f32x4)0.f; acc[1] = (f32x4)0.f;
        #pragma unroll
        for (int kt = 0; kt < 4; ++kt) {
            int row = wr*16 + lr;
            int slot = ((kt*4 + lk) ^ (row & 7)) * 8;
            f16x8 e = *(const f16x8*)&E[row*128 + slot];
            #pragma unroll
            for (int nt = 0; nt < 2; ++nt) {
                int cw = wc*32 + nt*16 + lr;
                f16x8 bh = *(const f16x8*)&WmL[cw*128 + (((kt*4 + lk) ^ (lr & 7)) * 8)];
                MFMA(e, bh, acc[nt]);
            }
        }
        // ---- msg epilogue ----
        float pr0 = 0.f, pr1 = 0.f;
        #pragma unroll
        for (int q = 0; q < 4; ++q) {
            int j = wr*16 + lk*4 + q;
            float v0 = lrelu(acc[0][q] + mb0) * m2v[q];
            float v1 = lrelu(acc[1][q] + mb1) * m2v[q];
            pr0 += v0; pr1 += v1;
            if (WOUT) { cs0[q] += v0; cs1[q] += v1; }
            if (j == i) {
                diag[(size_t)(rb+i)*NC + c0] = v0;
                diag[(size_t)(rb+i)*NC + c1] = v1;
            }
            if (WOUT) {
                Ust[tel(j, c0)] = (_Float16)v0;
                Ust[tel(j, c1)] = (_Float16)v1;
            }
        }
        pr0 += __shfl_xor(pr0, 16); pr0 += __shfl_xor(pr0, 32);
        pr1 += __shfl_xor(pr1, 16); pr1 += __shfl_xor(pr1, 32);
        if (l < 16) { Ls2[wr*128 + c0] = pr0; Ls2[wr*128 + c1] = pr1; }
        __syncthreads();   // B2: Ust + Ls2 ready; PA/PB writes visible
        if (WOUT) {
            size_t t0 = (size_t)(rb + i) * TILE;
            *(f16x8*)&Uo[t0 + (size_t)tid*8] = *(const f16x8*)&Ust[tid*8];
        }
        if (tid < 128)
            rsum[(size_t)(rb+i)*NC + tid] =
                (Ls2[tid] + Ls2[128+tid] + Ls2[256+tid] + Ls2[384+tid]) / AVGF;
    }
    if (WOUT) {
        const size_t RN = (size_t)NB * NN * NC;
        #pragma unroll
        for (int q = 0; q < 4; ++q) {
            int j = wr*16 + lk*4 + q;
            pcsum[(size_t)chunk * RN + (size_t)(rb+j)*NC + c0] = cs0[q];
            pcsum[(size_t)chunk * RN + (size_t)(rb+j)*NC + c1] = cs1[q];
        }
    }
}

// ---------------- red3 via MFMA: 128 blocks = 32b x 4 row-quarters ----------------
__global__ __launch_bounds__(512, 2) void k_red3(
    const float* __restrict__ rsum, const float* __restrict__ pcsum,
    const float* __restrict__ diag, const _Float16* __restrict__ Wt,
    const float* __restrict__ Weq, const float* __restrict__ eqb,
    const float* __restrict__ eqbd,
    float* __restrict__ A, float* __restrict__ Bc, float* __restrict__ Dgv,
    float* __restrict__ G, float* __restrict__ Gd)
{
    __shared__ __align__(16) char smem[50176];
    _Float16* Pd = (_Float16*)smem;            // [16][128] tel layout
    _Float16* Pr = Pd + 2048;
    _Float16* Pc = Pr + 2048;
    _Float16* WL = Pc + 2048;                  // [128][128] swizzled, 32KB
    float* tsp  = (float*)(smem + 45056);      // [4][128]
    float* trsp = tsp + 512;                   // [4][128]
    float* ts   = trsp + 512;                  // [128]
    float* trs  = ts + 128;                    // [128]
    int tid = threadIdx.x;
    int wg = blockIdx.x;
    int b = (wg & 7) * 4 + ((wg >> 3) & 3);    // xcd-affine
    int quarter = wg >> 5;
    int row0 = quarter * 16;
    const int rb = b * NN;
    const size_t RN = (size_t)NB * NN * NC;
    int w = tid >> 6, l = tid & 63, lr = l & 15, lk = l >> 4;
    int col = w * 16 + lr;                     // wave w owns 16 cols

    // ---- stage d/r panels ----
    {
        int s = tid & 255, prow = s >> 4, pks = s & 15;
        const float* src = (tid < 256 ? diag : rsum) + (size_t)(rb + row0 + prow) * NC + pks * 8;
        float4 f0 = *(const float4*)src, f1 = *(const float4*)(src + 4);
        float vv[8] = {f0.x,f0.y,f0.z,f0.w,f1.x,f1.y,f1.z,f1.w};
        f16x8 hv;
        #pragma unroll
        for (int q = 0; q < 8; ++q) hv[q] = (_Float16)vv[q];
        _Float16* dst = (tid < 256 ? Pd : Pr);
        *(f16x8*)&dst[prow*128 + ((pks ^ (prow & 7)) * 8)] = hv;
    }
    // ---- stage cl panel (sum 8 chunks) ----
    {
        int prow = tid >> 5, kq = tid & 31;
        size_t o = (size_t)(rb + row0 + prow) * NC + kq * 4;
        float s0 = 0, s1 = 0, s2 = 0, s3 = 0;
        #pragma unroll
        for (int ch = 0; ch < 8; ++ch) {
            float4 v = *(const float4*)&pcsum[(size_t)ch * RN + o];
            s0 += v.x; s1 += v.y; s2 += v.z; s3 += v.w;
        }
        f16x4 hv;
        hv[0] = (_Float16)(s0 / AVGF); hv[1] = (_Float16)(s1 / AVGF);
        hv[2] = (_Float16)(s2 / AVGF); hv[3] = (_Float16)(s3 / AVGF);
        *(f16x4*)&Pc[prow*128 + (((kq >> 1) ^ (prow & 7)) << 3) + (kq & 1) * 4] = hv;
    }
    // ---- quarter-0: ts/trs partials ----
    if (quarter == 0) {
        int c = tid & 127, part = tid >> 7;
        float st = 0.f, sd = 0.f;
        for (int ii = part*16; ii < part*16 + 16; ++ii) {
            st += rsum[(size_t)(rb+ii)*NC + c];
            sd += diag[(size_t)(rb+ii)*NC + c];
        }
        tsp[part*128 + c] = st;
        trsp[part*128 + c] = sd;
    }
    // ---- prefetch W matrix 0 ----
    f16x8 wreg[4];
    #pragma unroll
    for (int it = 0; it < 4; ++it) {
        int s = tid + it*512, c = s >> 4, ks = s & 15;
        wreg[it] = *(const f16x8*)&Wt[c*128 + ks*8];
    }
    __syncthreads();
    #pragma unroll
    for (int it = 0; it < 4; ++it) {
        int s = tid + it*512, c = s >> 4, ks = s & 15;
        *(f16x8*)&WL[c*128 + ((ks ^ (c & 7)) * 8)] = wreg[it];
    }
    if (quarter == 0 && tid < 256) {
        int c = tid & 127;
        float* dst = (tid < 128 ? ts : trs);
        float* src = (tid < 128 ? tsp : trsp);
        dst[c] = (src[c] + src[128+c] + src[256+c] + src[384+c]) / AVGF;
    }

    f32x4 acc3[3];
    acc3[0] = (f32x4)0.f; acc3[1] = (f32x4)0.f; acc3[2] = (f32x4)0.f;
    const int pan[9] = {0,0,0,1,1,2,2,1,2};  // basis 2..10 -> d/r/cl
    const int outp[9] = {2,0,1,0,1,0,1,2,2}; // basis 2..10 -> Dg/A/Bc
    #pragma unroll
    for (int m = 0; m < 9; ++m) {
        __syncthreads();   // WL(m) visible
        if (m < 8) {
            const _Float16* Wn = Wt + (size_t)(m+1) * 16384;
            #pragma unroll
            for (int it = 0; it < 4; ++it) {
                int s = tid + it*512, c = s >> 4, ks = s & 15;
                wreg[it] = *(const f16x8*)&Wn[c*128 + ks*8];
            }
        }
        const _Float16* P = (pan[m] == 0 ? Pd : pan[m] == 1 ? Pr : Pc);
        #pragma unroll
        for (int kt = 0; kt < 4; ++kt) {
            f16x8 a = *(const f16x8*)&P[lr*128 + (((kt*4+lk) ^ (lr & 7)) * 8)];
            f16x8 bb = *(const f16x8*)&WL[col*128 + (((kt*4+lk) ^ (lr & 7)) * 8)];
            MFMA(a, bb, acc3[outp[m]]);
        }
        __syncthreads();   // MFMA reads of WL done
        if (m < 8) {
            #pragma unroll
            for (int it = 0; it < 4; ++it) {
                int s = tid + it*512, c = s >> 4, ks = s & 15;
                *(f16x8*)&WL[c*128 + ((ks ^ (c & 7)) * 8)] = wreg[it];
            }
        }
    }
    #pragma unroll
    for (int q = 0; q < 4; ++q) {
        size_t o = (size_t)(rb + row0 + lk*4 + q) * NC + col;
        A[o]   = acc3[0][q];
        Bc[o]  = acc3[1][q];
        Dgv[o] = acc3[2][q];
    }
    if (quarter == 0) {
        __syncthreads();
        int c = tid & 127, part = tid >> 7;
        float g = 0.f, gd = 0.f;
        for (int k = part*32; k < part*32 + 32; ++k) {
            float tv = ts[k], rv = trs[k];
            g  += tv * Weq[(11*NC + k)*NC + c] + rv * Weq[(13*NC + k)*NC + c];
            gd += tv * Weq[(12*NC + k)*NC + c] + rv * Weq[(14*NC + k)*NC + c];
        }
        tsp[part*128 + c] = g;
        trsp[part*128 + c] = gd;
        __syncthreads();
        if (tid < 128) {
            float gg = eqb[tid] + tsp[tid] + tsp[128+tid] + tsp[256+tid] + tsp[384+tid];
            float gdd = eqbd[tid] + trsp[tid] + trsp[128+tid] + trsp[256+tid] + trsp[384+tid];
            G[b*NC + tid] = gg;
            Gd[b*NC + tid] = gdd;
        }
    }
}

// ---------------- Eq2to0 head + output MLP ----------------
__global__ __launch_bounds__(128) void k_final(
    const float* __restrict__ rsum, const float* __restrict__ diag,
    const float* __restrict__ w20, const float* __restrict__ b20,
    const float* __restrict__ wmlp, const float* __restrict__ bmlp,
    float* __restrict__ outp)
{
    int b = blockIdx.x;
    int c = threadIdx.x;
    __shared__ float agg0[NC], agg1[NC], act3[NC];
    float dgv = 0.f, tot = 0.f;
    for (int i = 0; i < NN; ++i) {
        dgv += diag[(size_t)(b * NN + i) * NC + c];
        tot += rsum[(size_t)(b * NN + i) * NC + c];
    }
    agg0[c] = lrelu(dgv / AVGF);
    agg1[c] = lrelu(tot / AVGF);
    __syncthreads();
    float a3 = b20[c];
    for (int k = 0; k < NC; ++k)
        a3 += agg0[k] * w20[k * NC + c] + agg1[k] * w20[(NC + k) * NC + c];
    act3[c] = a3;
    __syncthreads();
    if (c < 2) {
        float o = bmlp[c];
        for (int d = 0; d < NC; ++d) o += act3[d] * wmlp[d * 2 + c];
        outp[b * 2 + c] = o;
    }
}

extern "C" void kernel_launch(void* const* d_in, const int* in_sizes, int n_in,
                              void* d_out, int out_size, void* d_ws, size_t ws_size,
                              hipStream_t stream)
{
    const float* momenta = (const float*)d_in[0];
    const float* scalars = (const float*)d_in[1];
    const int*   nobj    = (const int*)d_in[2];
    const float* w_lin   = (const float*)d_in[3];
    const float* alpha   = (const float*)d_in[4];
    const float* w_in    = (const float*)d_in[5];
    const float* b_in    = (const float*)d_in[6];
    const float *msgW[4], *msgB[4], *eqW[4], *eqB[4], *eqBd[4];
    const float *wm0, *bm0, *w20, *b20, *wmlp, *bmlp;
    if (n_in >= 33) {
        for (int l = 0; l < 4; ++l) {
            msgW[l] = (const float*)d_in[7 + l];
            msgB[l] = (const float*)d_in[11 + l];
            eqW[l]  = (const float*)d_in[15 + l];
            eqB[l]  = (const float*)d_in[19 + l];
            eqBd[l] = (const float*)d_in[23 + l];
        }
        wm0  = (const float*)d_in[27]; bm0  = (const float*)d_in[28];
        w20  = (const float*)d_in[29]; b20  = (const float*)d_in[30];
        wmlp = (const float*)d_in[31]; bmlp = (const float*)d_in[32];
    } else {
        for (int l = 0; l < 4; ++l) {
            msgW[l] = (const float*)d_in[7] + (size_t)l * NC * NC;
            msgB[l] = (const float*)d_in[8] + l * NC;
            eqW[l]  = (const float*)d_in[9] + (size_t)l * 15 * NC * NC;
            eqB[l]  = (const float*)d_in[10] + l * NC;
            eqBd[l] = (const float*)d_in[11] + l * NC;
        }
        wm0  = (const float*)d_in[12]; bm0  = (const float*)d_in[13];
        w20  = (const float*)d_in[14]; b20  = (const float*)d_in[15];
        wmlp = (const float*)d_in[16]; bmlp = (const float*)d_in[17];
    }

    // ---- workspace layout ----
    const size_t TN2 = (size_t)NB * NN * TILE;       // fp16 elems per tile array
    const size_t RN  = (size_t)NB * NN * NC;         // floats per row-vector array
    _Float16* X  = (_Float16*)d_ws;
    _Float16* Y  = X + TN2;
    _Float16* SW = Y + TN2;                          // 49 * 16384 fp16
    float* fp = (float*)(((uintptr_t)(SW + 49 * 16384) + 15) & ~(uintptr_t)15);
    float* rsum  = fp;
    float* pcsum = rsum + RN;                        // 8 chunks
    float* diag  = pcsum + 8 * RN;
    float* Aa    = diag + RN;
    float* Bb    = Aa + RN;
    float* Dgv   = Bb + RN;
    float* G     = Dgv + RN;
    float* Gd    = G + NB * NC;
    float* mask1 = Gd + NB * NC;
    float* P0    = mask1 + NB * NN;
    float* P1    = P0 + (size_t)NB * NN * NCS;
    float* P2    = P1 + (size_t)NB * NN * NCS;
    float* Ps3   = P2 + (size_t)NB * NN * NCS;
    float* Ps4   = Ps3 + NB * NCS;
    size_t need = (size_t)((char*)(Ps4 + NB * NCS) - (char*)d_ws);
    if (ws_size < need) return;

    k_split<<<dim3(64, 49), 256, 0, stream>>>(msgW[0], msgW[1], msgW[2], msgW[3],
                                              wm0, eqW[0], eqW[1], eqW[2], eqW[3], SW);
    k_prep<<<NB, 256, 0, stream>>>(scalars, nobj, w_in, mask1, P0, P1, P2, Ps3, Ps4);

    k_f0<<<256, 512, 0, stream>>>(momenta, mask1, P0, P1, P2, Ps3, Ps4,
                                  b_in, w_lin, alpha, SW /*msgW[0]*/,
                                  msgB[0], X, rsum, diag, pcsum);

    _Float16 *in = X, *out = Y;
    for (int l = 0; l < 4; ++l) {
        _Float16* Wt = SW + (size_t)(13 + l * 9) * 16384;
        k_red3<<<128, 512, 0, stream>>>(rsum, pcsum, diag, Wt, eqW[l],
                                        eqB[l], eqBd[l], Aa, Bb, Dgv, G, Gd);
        _Float16* W0 = SW + (size_t)(5 + 2 * l) * 16384;
        _Float16* W1 = W0 + 16384;
        if (l < 3) {
            _Float16* Wm = SW + (size_t)(l + 1) * 16384;
            k_feq<1><<<256, 1024, 0, stream>>>(in, W0, W1, Wm, msgB[l + 1],
                                               Aa, Bb, Dgv, G, Gd, mask1,
                                               out, rsum, diag, pcsum);
            _Float16* t = in; in = out; out = t;
        } else {
            _Float16* Wm = SW + (size_t)4 * 16384;    // wm0
            k_feq<0><<<256, 1024, 0, stream>>>(in, W0, W1, Wm, bm0,
                                               Aa, Bb, Dgv, G, Gd, mask1,
                                               out, rsum, diag, pcsum);
        }
    }
    k_final<<<NB, 128, 0, stream>>>(rsum, diag, w20, b20, wmlp, bmlp, (float*)d_out);
}

// Round 14
// 242.697 us; speedup vs baseline: 2.5647x; 1.8567x over previous
//
#include <hip/hip_runtime.h>
#include <math.h>

#define NB 32
#define NN 64
#define NS 9
#define NCS 32
#define NC 128
#define AVGF 49.0f
#define TILE 8192   // fp16 elems per (b,i) tile: 64 rows x 128 ch

typedef __attribute__((ext_vector_type(8))) _Float16 f16x8;
typedef __attribute__((ext_vector_type(4))) _Float16 f16x4;
typedef __attribute__((ext_vector_type(4))) float f32x4;

#define MFMA(a,bb,c) c = __builtin_amdgcn_mfma_f32_16x16x32_f16(a,bb,c,0,0,0)

__device__ __forceinline__ float lrelu(float x){ return x>0.f ? x : 0.01f*x; }
// swizzled tile element address for (row j, channel c): 16B-slot XOR swizzle
__device__ __forceinline__ int tel(int j,int c){ return j*128 + (((c>>3)^(j&7))<<3) + (c&7); }

// ---------------- convert weights: W[k][c] fp32 -> [c][k] fp16 ----------------
// m 0..4: msgW0..3, wm0 | 5..12: eqW l W0/W1 | 13..48: eqW l basis 2..10
__global__ __launch_bounds__(256) void k_split(
    const float* __restrict__ m0, const float* __restrict__ m1,
    const float* __restrict__ m2, const float* __restrict__ m3,
    const float* __restrict__ m4, const float* __restrict__ e0,
    const float* __restrict__ e1, const float* __restrict__ e2,
    const float* __restrict__ e3, _Float16* __restrict__ outbuf)
{
    int m = blockIdx.y;
    const float* src;
    if (m < 5) src = (m == 0 ? m0 : m == 1 ? m1 : m == 2 ? m2 : m == 3 ? m3 : m4);
    else if (m < 13) {
        int l = (m - 5) >> 1, sub = (m - 5) & 1;
        const float* e = (l == 0 ? e0 : l == 1 ? e1 : l == 2 ? e2 : e3);
        src = e + sub * NC * NC;
    } else {
        int l = (m - 13) / 9, idx = (m - 13) % 9;
        const float* e = (l == 0 ? e0 : l == 1 ? e1 : l == 2 ? e2 : e3);
        src = e + (size_t)(2 + idx) * NC * NC;
    }
    int idx2 = blockIdx.x * 256 + threadIdx.x;
    int k = idx2 >> 7, c = idx2 & 127;
    outbuf[(size_t)m * 16384 + c * NC + k] = (_Float16)src[idx2];
}

// ---------------- prep: mask1, eq1to2 projections ----------------
__global__ __launch_bounds__(256) void k_prep(
    const float* __restrict__ scalars, const int* __restrict__ nobj,
    const float* __restrict__ w_in,
    float* __restrict__ mask1, float* __restrict__ P0,
    float* __restrict__ P1, float* __restrict__ P2,
    float* __restrict__ Ps3, float* __restrict__ Ps4)
{
    int b = blockIdx.x, tid = threadIdx.x;
    __shared__ float xs[NN][NS];
    __shared__ float ss[NS];
    int cnt = nobj[b];
    for (int idx = tid; idx < NN * NS; idx += 256) {
        int i = idx / NS, s = idx - i * NS;
        xs[i][s] = (i < cnt) ? scalars[(b * NN + i) * NS + s] : 0.0f;
    }
    if (tid < NN) mask1[b * NN + tid] = (tid < cnt) ? 1.0f : 0.0f;
    __syncthreads();
    if (tid < NS) {
        float a = 0.f;
        for (int i = 0; i < NN; ++i) a += xs[i][tid];
        ss[tid] = a / AVGF;
    }
    __syncthreads();
    for (int idx = tid; idx < NN * NCS; idx += 256) {
        int i = idx >> 5, d = idx & 31;
        float a0 = 0.f, a1 = 0.f, a2 = 0.f;
        #pragma unroll
        for (int s = 0; s < NS; ++s) {
            float x = xs[i][s];
            a0 += x * w_in[(0 * NS + s) * NCS + d];
            a1 += x * w_in[(1 * NS + s) * NCS + d];
            a2 += x * w_in[(2 * NS + s) * NCS + d];
        }
        P0[(b * NN + i) * NCS + d] = a0;
        P1[(b * NN + i) * NCS + d] = a1;
        P2[(b * NN + i) * NCS + d] = a2;
    }
    if (tid < NCS) {
        float a3 = 0.f, a4 = 0.f;
        #pragma unroll
        for (int s = 0; s < NS; ++s) {
            a3 += ss[s] * w_in[(3 * NS + s) * NCS + tid];
            a4 += ss[s] * w_in[(4 * NS + s) * NCS + tid];
        }
        Ps3[b * NCS + tid] = a3;
        Ps4[b * NCS + tid] = a4;
    }
}

// ---------------- F0 persistent: 4 tiles/block (512 blocks); no launch_bounds cap ----------------
__global__ __launch_bounds__(512, 2) void k_f0(
    const float* __restrict__ momenta, const float* __restrict__ mask1,
    const float* __restrict__ P0, const float* __restrict__ P1,
    const float* __restrict__ P2, const float* __restrict__ Ps3,
    const float* __restrict__ Ps4, const float* __restrict__ b_in,
    const float* __restrict__ w_lin, const float* __restrict__ alpha,
    const _Float16* __restrict__ Wm, const float* __restrict__ bias,
    _Float16* __restrict__ U, float* __restrict__ rsum, float* __restrict__ diag,
    float* __restrict__ pcsum)
{
    __shared__ __align__(16) char smem[44672];
    _Float16* E   = (_Float16*)smem;                  // [0,16K)
    _Float16* Ust = E + TILE;                         // [16K,32K)
    float* mom  = (float*)(smem + 32768);             // [64][4]
    float* P1s  = mom + 256;                          // [64][32]
    float* psb  = P1s + 2048;                         // [32] Ps3+b_in
    float* wl   = psb + 32;                           // [96]
    float* al   = wl + 96;                            // [96]
    float* dots = al + 96;                            // [64]
    float* mjv  = dots + 64;                          // [64]
    float* pp0  = mjv + 64;                           // [32]
    float* pp2  = pp0 + 32;                           // [32] P2+Ps4
    float* Ls2  = pp2 + 32;                           // [2][128]
    int tid = threadIdx.x;
    int wg = blockIdx.x;
    int b = (wg & 7) * 4 + ((wg >> 3) & 3);           // xcd-affine
    int chunk = wg >> 5;                              // 0..15
    int i0 = chunk * 4;
    const int rb = b * NN;
    int w = tid >> 6, l = tid & 63, lr = l & 15, lk = l >> 4;
    int wr = w >> 2, wc = w & 3;
    int c0 = wc * 32 + lr, c1 = c0 + 16;
    // ---- once-per-block staging ----
    if (tid < 64) {
        *(float4*)&mom[tid*4] = *(const float4*)&momenta[(size_t)(rb + tid) * 4];
        mjv[tid] = mask1[rb + tid];
    }
    *(float4*)&P1s[tid*4] = *(const float4*)&P1[(size_t)rb * NCS + tid*4];
    if (tid < 32) psb[tid] = Ps3[b*NCS + tid] + b_in[tid];
    if (tid >= 64 && tid < 160) { wl[tid-64] = w_lin[tid-64]; al[tid-64] = alpha[tid-64]; }
    // W into registers
    f16x8 wmr[4][2];
    {
        const int cb = c0 * NC + lk * 8;
        #pragma unroll
        for (int kt = 0; kt < 4; ++kt)
            #pragma unroll
            for (int nt = 0; nt < 2; ++nt)
                wmr[kt][nt] = *(const f16x8*)&Wm[cb + nt*16*NC + kt*32];
    }
    float bs0 = bias[c0], bs1 = bias[c1];
    float mjc[2][4];
    #pragma unroll
    for (int mt = 0; mt < 2; ++mt)
        #pragma unroll
        for (int q = 0; q < 4; ++q)
            mjc[mt][q] = mask1[rb + (wr*2 + mt)*16 + lk*4 + q];
    float cs0[2][4], cs1[2][4];
    #pragma unroll
    for (int mt = 0; mt < 2; ++mt)
        #pragma unroll
        for (int q = 0; q < 4; ++q) { cs0[mt][q] = 0.f; cs1[mt][q] = 0.f; }

    int pj = tid >> 4, pks = tid & 15, pc0 = pks * 8;
    for (int t = 0; t < 4; ++t) {
        int i = i0 + t;
        float mi = mjv[i];
        if (tid < 64) {
            dots[tid] = mom[i*4+0]*mom[tid*4+0] - mom[i*4+1]*mom[tid*4+1]
                      - mom[i*4+2]*mom[tid*4+2] - mom[i*4+3]*mom[tid*4+3];
        } else if (tid < 96) {
            int c = tid - 64;
            pp0[c] = P0[(size_t)(rb+i)*NCS + c];
            pp2[c] = P2[(size_t)(rb+i)*NCS + c] + Ps4[b*NCS + c];
        }
        __syncthreads();   // B0
        // ---- build T0 tile -> E ----
        #pragma unroll
        for (int it = 0; it < 2; ++it) {
            int j = pj + it * 32;
            float m2 = mi * mjv[j];
            float v[8];
            if (pks < 4) {
                #pragma unroll
                for (int q = 0; q < 8; ++q) {
                    float x = pp0[pc0+q] + P1s[j*NCS + pc0+q] + psb[pc0+q];
                    if (j == i) x += pp2[pc0+q];
                    v[q] = lrelu(x) * m2;
                }
            } else {
                int c2 = pc0 - NCS;
                float dj = dots[j];
                #pragma unroll
                for (int q = 0; q < 8; ++q) {
                    float r = dj * wl[c2+q];
                    float lg = __log2f(1.0f + fabsf(r));
                    float s = al[c2+q] * 0.69314718f * lg;
                    v[q] = __uint_as_float(__float_as_uint(s) ^ (__float_as_uint(r) & 0x80000000u)) * m2;
                }
            }
            f16x8 hv;
            #pragma unroll
            for (int q = 0; q < 8; ++q) hv[q] = (_Float16)v[q];
            *(f16x8*)&E[j*128 + ((pks ^ (j & 7)) * 8)] = hv;
        }
        __syncthreads();   // B1
        // ---- msg MFMA ----
        f32x4 acc[2][2];
        acc[0][0]=(f32x4)0.f; acc[0][1]=(f32x4)0.f; acc[1][0]=(f32x4)0.f; acc[1][1]=(f32x4)0.f;
        #pragma unroll
        for (int kt = 0; kt < 4; ++kt)
            #pragma unroll
            for (int mt = 0; mt < 2; ++mt) {
                int row = (wr*2 + mt)*16 + lr;
                int slot = ((kt*4 + lk) ^ (row & 7)) * 8;
                f16x8 a = *(const f16x8*)&E[row*128 + slot];
                #pragma unroll
                for (int nt = 0; nt < 2; ++nt)
                    MFMA(a, wmr[kt][nt], acc[mt][nt]);
            }
        // ---- fragment epilogue ----
        float pr0 = 0.f, pr1 = 0.f;
        #pragma unroll
        for (int mt = 0; mt < 2; ++mt)
            #pragma unroll
            for (int q = 0; q < 4; ++q) {
                int j = (wr*2 + mt)*16 + lk*4 + q;
                float m2 = mi * mjc[mt][q];
                float v0 = lrelu(acc[mt][0][q] + bs0) * m2;
                float v1 = lrelu(acc[mt][1][q] + bs1) * m2;
                pr0 += v0; pr1 += v1;
                cs0[mt][q] += v0; cs1[mt][q] += v1;
                if (j == i) {
                    diag[(size_t)(rb+i)*NC + c0] = v0;
                    diag[(size_t)(rb+i)*NC + c1] = v1;
                }
                Ust[tel(j, c0)] = (_Float16)v0;
                Ust[tel(j, c1)] = (_Float16)v1;
            }
        pr0 += __shfl_xor(pr0, 16); pr0 += __shfl_xor(pr0, 32);
        pr1 += __shfl_xor(pr1, 16); pr1 += __shfl_xor(pr1, 32);
        if (l < 16) { Ls2[wr*128 + c0] = pr0; Ls2[wr*128 + c1] = pr1; }
        __syncthreads();   // B2
        size_t t0 = (size_t)(rb + i) * TILE;
        *(f16x8*)&U[t0 + (size_t)tid*8] = *(const f16x8*)&Ust[tid*8];
        *(f16x8*)&U[t0 + (size_t)(tid+512)*8] = *(const f16x8*)&Ust[(tid+512)*8];
        if (tid < 128)
            rsum[(size_t)(rb+i)*NC + tid] = (Ls2[tid] + Ls2[128 + tid]) / AVGF;
    }
    const size_t RN = (size_t)NB * NN * NC;
    #pragma unroll
    for (int mt = 0; mt < 2; ++mt)
        #pragma unroll
        for (int q = 0; q < 4; ++q) {
            int j = (wr*2 + mt)*16 + lk*4 + q;
            pcsum[(size_t)chunk * RN + (size_t)(rb+j)*NC + c0] = cs0[mt][q];
            pcsum[(size_t)chunk * RN + (size_t)(rb+j)*NC + c1] = cs1[mt][q];
        }
}

// ---------------- F_eq persistent: r11-verified — 8 tiles/block, all W in regs, single-buffer ----------------
template<int WOUT>
__global__ __launch_bounds__(512, 2) void k_feq(
    const _Float16* __restrict__ Uin,
    const _Float16* __restrict__ W0, const _Float16* __restrict__ W1,
    const _Float16* __restrict__ Wm, const float* __restrict__ mbias,
    const float* __restrict__ A, const float* __restrict__ Bc,
    const float* __restrict__ Dgv, const float* __restrict__ G,
    const float* __restrict__ Gd, const float* __restrict__ mask1,
    _Float16* __restrict__ Uo, float* __restrict__ rsum, float* __restrict__ diag,
    float* __restrict__ pcsum)
{
    __shared__ __align__(16) char smem[66560];
    _Float16* PA  = (_Float16*)smem;              // [0,16K)
    _Float16* PB  = (_Float16*)(smem + 16384);    // [16K,32K)
    _Float16* E   = (_Float16*)(smem + 32768);    // [32K,48K)
    _Float16* Ust = (_Float16*)(smem + 49152);    // [48K,64K)
    float* Ls2    = (float*)(smem + 65536);       // [2][128]
    int tid = threadIdx.x;
    int wg = blockIdx.x;
    int b = (wg & 7) * 4 + ((wg >> 3) & 3);       // xcd-affine
    int chunk = wg >> 5;                          // 0..7
    int i0 = chunk * 8;
    const int rb = b * NN;
    int w = tid >> 6, l = tid & 63, lr = l & 15, lk = l >> 4;
    int wr = w >> 2, wc = w & 3;
    int c0 = wc * 32 + lr, c1 = c0 + 16;

    // ---- W into registers (once per kernel) ----
    f16x8 w0r[4][2], w1r[4][2], wmr[4][2];
    {
        const int cb = c0 * NC + lk * 8;
        #pragma unroll
        for (int kt = 0; kt < 4; ++kt)
            #pragma unroll
            for (int nt = 0; nt < 2; ++nt) {
                w0r[kt][nt] = *(const f16x8*)&W0[cb + nt*16*NC + kt*32];
                w1r[kt][nt] = *(const f16x8*)&W1[cb + nt*16*NC + kt*32];
                wmr[kt][nt] = *(const f16x8*)&Wm[cb + nt*16*NC + kt*32];
            }
    }
    // ---- i-invariant epilogue constants ----
    float G0 = G[(size_t)b*NC + c0], G1 = G[(size_t)b*NC + c1];
    float Gd0 = Gd[(size_t)b*NC + c0], Gd1 = Gd[(size_t)b*NC + c1];
    float mb0 = mbias[c0], mb1 = mbias[c1];
    float Bv0[2][4], Bv1[2][4], mjc[2][4], cs0[2][4], cs1[2][4];
    #pragma unroll
    for (int mt = 0; mt < 2; ++mt)
        #pragma unroll
        for (int q = 0; q < 4; ++q) {
            int j = (wr*2 + mt)*16 + lk*4 + q;
            Bv0[mt][q] = Bc[(size_t)(rb+j)*NC + c0];
            Bv1[mt][q] = Bc[(size_t)(rb+j)*NC + c1];
            mjc[mt][q] = mask1[rb + j];
            cs0[mt][q] = 0.f; cs1[mt][q] = 0.f;
        }

    int sj = tid >> 4, sks = tid & 15;
    // ---- prologue: stage tile i0 ----
    {
        size_t t0 = (size_t)(rb + i0) * TILE;
        int isw = i0 & 7;
        f16x8 r0 = *(const f16x8*)&Uin[t0 + (size_t)tid*8];
        f16x8 r1 = *(const f16x8*)&Uin[t0 + (size_t)(tid+512)*8];
        f16x8 r2 = *(const f16x8*)&Uin[(size_t)(rb+sj)*TILE + i0*128 + ((sks^isw)*8)];
        f16x8 r3 = *(const f16x8*)&Uin[(size_t)(rb+sj+32)*TILE + i0*128 + ((sks^isw)*8)];
        *(f16x8*)&PA[tid*8] = r0;
        *(f16x8*)&PA[(tid+512)*8] = r1;
        *(f16x8*)&PB[sj*128 + ((sks^(sj&7))*8)] = r2;
        *(f16x8*)&PB[(sj+32)*128 + ((sks^((sj+32)&7))*8)] = r3;
    }
    __syncthreads();

    for (int t = 0; t < 8; ++t) {
        int i = i0 + t;
        float mi = mask1[rb + i];
        float A0v = A[(size_t)(rb+i)*NC + c0] + G0;
        float A1v = A[(size_t)(rb+i)*NC + c1] + G1;
        float D0v = Dgv[(size_t)(rb+i)*NC + c0] + Gd0;
        float D1v = Dgv[(size_t)(rb+i)*NC + c1] + Gd1;
        // issue next-tile staging loads (written into PA/PB after B1)
        f16x8 r0, r1, r2, r3;
        if (t < 7) {
            int in_ = i + 1;
            size_t t0n = (size_t)(rb + in_) * TILE;
            int isw = in_ & 7;
            r0 = *(const f16x8*)&Uin[t0n + (size_t)tid*8];
            r1 = *(const f16x8*)&Uin[t0n + (size_t)(tid+512)*8];
            r2 = *(const f16x8*)&Uin[(size_t)(rb+sj)*TILE + in_*128 + ((sks^isw)*8)];
            r3 = *(const f16x8*)&Uin[(size_t)(rb+sj+32)*TILE + in_*128 + ((sks^isw)*8)];
        }
        // ---- eq MFMA: U@W0 + U^T@W1 ----
        f32x4 acc[2][2];
        acc[0][0]=(f32x4)0.f; acc[0][1]=(f32x4)0.f; acc[1][0]=(f32x4)0.f; acc[1][1]=(f32x4)0.f;
        #pragma unroll
        for (int kt = 0; kt < 4; ++kt)
            #pragma unroll
            for (int mt = 0; mt < 2; ++mt) {
                int row = (wr*2 + mt)*16 + lr;
                int slot = ((kt*4 + lk) ^ (row & 7)) * 8;
                f16x8 a1 = *(const f16x8*)&PA[row*128 + slot];
                f16x8 a2 = *(const f16x8*)&PB[row*128 + slot];
                #pragma unroll
                for (int nt = 0; nt < 2; ++nt) {
                    MFMA(a1, w0r[kt][nt], acc[mt][nt]);
                    MFMA(a2, w1r[kt][nt], acc[mt][nt]);
                }
            }
        // ---- broadcast epilogue -> E ----
        float m2v[2][4];
        #pragma unroll
        for (int mt = 0; mt < 2; ++mt)
            #pragma unroll
            for (int q = 0; q < 4; ++q) {
                int j = (wr*2 + mt)*16 + lk*4 + q;
                float m2 = mi * mjc[mt][q];
                m2v[mt][q] = m2;
                float v0 = acc[mt][0][q] + A0v + Bv0[mt][q];
                float v1 = acc[mt][1][q] + A1v + Bv1[mt][q];
                if (j == i) { v0 += D0v; v1 += D1v; }
                v0 = lrelu(v0) * m2;
                v1 = lrelu(v1) * m2;
                E[tel(j, c0)] = (_Float16)v0;
                E[tel(j, c1)] = (_Float16)v1;
            }
        __syncthreads();   // B1: E ready; ALL PA/PB reads done
        // stage-write next tile's panels (visible to next eq MFMA after B2)
        if (t < 7) {
            *(f16x8*)&PA[tid*8] = r0;
            *(f16x8*)&PA[(tid+512)*8] = r1;
            *(f16x8*)&PB[sj*128 + ((sks^(sj&7))*8)] = r2;
            *(f16x8*)&PB[(sj+32)*128 + ((sks^((sj+32)&7))*8)] = r3;
        }
        // ---- msg MFMA ----
        acc[0][0]=(f32x4)0.f; acc[0][1]=(f32x4)0.f; acc[1][0]=(f32x4)0.f; acc[1][1]=(f32x4)0.f;
        #pragma unroll
        for (int kt = 0; kt < 4; ++kt)
            #pragma unroll
            for (int mt = 0; mt < 2; ++mt) {
                int row = (wr*2 + mt)*16 + lr;
                int slot = ((kt*4 + lk) ^ (row & 7)) * 8;
                f16x8 e = *(const f16x8*)&E[row*128 + slot];
                #pragma unroll
                for (int nt = 0; nt < 2; ++nt)
                    MFMA(e, wmr[kt][nt], acc[mt][nt]);
            }
        // ---- msg epilogue ----
        float pr0 = 0.f, pr1 = 0.f;
        #pragma unroll
        for (int mt = 0; mt < 2; ++mt)
            #pragma unroll
            for (int q = 0; q < 4; ++q) {
                int j = (wr*2 + mt)*16 + lk*4 + q;
                float v0 = lrelu(acc[mt][0][q] + mb0) * m2v[mt][q];
                float v1 = lrelu(acc[mt][1][q] + mb1) * m2v[mt][q];
                pr0 += v0; pr1 += v1;
                if (WOUT) { cs0[mt][q] += v0; cs1[mt][q] += v1; }
                if (j == i) {
                    diag[(size_t)(rb+i)*NC + c0] = v0;
                    diag[(size_t)(rb+i)*NC + c1] = v1;
                }
                if (WOUT) {
                    Ust[tel(j, c0)] = (_Float16)v0;
                    Ust[tel(j, c1)] = (_Float16)v1;
                }
            }
        pr0 += __shfl_xor(pr0, 16); pr0 += __shfl_xor(pr0, 32);
        pr1 += __shfl_xor(pr1, 16); pr1 += __shfl_xor(pr1, 32);
        if (l < 16) { Ls2[wr*128 + c0] = pr0; Ls2[wr*128 + c1] = pr1; }
        __syncthreads();   // B2: Ust + Ls2 ready; PA/PB writes visible
        if (WOUT) {
            size_t t0 = (size_t)(rb + i) * TILE;
            *(f16x8*)&Uo[t0 + (size_t)tid*8] = *(const f16x8*)&Ust[tid*8];
            *(f16x8*)&Uo[t0 + (size_t)(tid+512)*8] = *(const f16x8*)&Ust[(tid+512)*8];
        }
        if (tid < 128)
            rsum[(size_t)(rb+i)*NC + tid] = (Ls2[tid] + Ls2[128 + tid]) / AVGF;
    }
    if (WOUT) {
        const size_t RN = (size_t)NB * NN * NC;
        #pragma unroll
        for (int mt = 0; mt < 2; ++mt)
            #pragma unroll
            for (int q = 0; q < 4; ++q) {
                int j = (wr*2 + mt)*16 + lk*4 + q;
                pcsum[(size_t)chunk * RN + (size_t)(rb+j)*NC + c0] = cs0[mt][q];
                pcsum[(size_t)chunk * RN + (size_t)(rb+j)*NC + c1] = cs1[mt][q];
            }
    }
}

// ---------------- red3 via MFMA: 128 blocks = 32b x 4 row-quarters; nch pcsum chunks ----------------
__global__ __launch_bounds__(512, 2) void k_red3(
    const float* __restrict__ rsum, const float* __restrict__ pcsum,
    const float* __restrict__ diag, const _Float16* __restrict__ Wt,
    const float* __restrict__ Weq, const float* __restrict__ eqb,
    const float* __restrict__ eqbd, int nch,
    float* __restrict__ A, float* __restrict__ Bc, float* __restrict__ Dgv,
    float* __restrict__ G, float* __restrict__ Gd)
{
    __shared__ __align__(16) char smem[50176];
    _Float16* Pd = (_Float16*)smem;            // [16][128] tel layout
    _Float16* Pr = Pd + 2048;
    _Float16* Pc = Pr + 2048;
    _Float16* WL = Pc + 2048;                  // [128][128] swizzled, 32KB
    float* tsp  = (float*)(smem + 45056);      // [4][128]
    float* trsp = tsp + 512;                   // [4][128]
    float* ts   = trsp + 512;                  // [128]
    float* trs  = ts + 128;                    // [128]
    int tid = threadIdx.x;
    int wg = blockIdx.x;
    int b = (wg & 7) * 4 + ((wg >> 3) & 3);    // xcd-affine
    int quarter = wg >> 5;
    int row0 = quarter * 16;
    const int rb = b * NN;
    const size_t RN = (size_t)NB * NN * NC;
    int w = tid >> 6, l = tid & 63, lr = l & 15, lk = l >> 4;
    int col = w * 16 + lr;                     // wave w owns 16 cols

    // ---- stage d/r panels ----
    {
        int s = tid & 255, prow = s >> 4, pks = s & 15;
        const float* src = (tid < 256 ? diag : rsum) + (size_t)(rb + row0 + prow) * NC + pks * 8;
        float4 f0 = *(const float4*)src, f1 = *(const float4*)(src + 4);
        float vv[8] = {f0.x,f0.y,f0.z,f0.w,f1.x,f1.y,f1.z,f1.w};
        f16x8 hv;
        #pragma unroll
        for (int q = 0; q < 8; ++q) hv[q] = (_Float16)vv[q];
        _Float16* dst = (tid < 256 ? Pd : Pr);
        *(f16x8*)&dst[prow*128 + ((pks ^ (prow & 7)) * 8)] = hv;
    }
    // ---- stage cl panel (sum nch chunks) ----
    {
        int prow = tid >> 5, kq = tid & 31;
        size_t o = (size_t)(rb + row0 + prow) * NC + kq * 4;
        float s0 = 0, s1 = 0, s2 = 0, s3 = 0;
        for (int ch = 0; ch < nch; ++ch) {
            float4 v = *(const float4*)&pcsum[(size_t)ch * RN + o];
            s0 += v.x; s1 += v.y; s2 += v.z; s3 += v.w;
        }
        f16x4 hv;
        hv[0] = (_Float16)(s0 / AVGF); hv[1] = (_Float16)(s1 / AVGF);
        hv[2] = (_Float16)(s2 / AVGF); hv[3] = (_Float16)(s3 / AVGF);
        *(f16x4*)&Pc[prow*128 + (((kq >> 1) ^ (prow & 7)) << 3) + (kq & 1) * 4] = hv;
    }
    // ---- quarter-0: ts/trs partials ----
    if (quarter == 0) {
        int c = tid & 127, part = tid >> 7;
        float st = 0.f, sd = 0.f;
        for (int ii = part*16; ii < part*16 + 16; ++ii) {
            st += rsum[(size_t)(rb+ii)*NC + c];
            sd += diag[(size_t)(rb+ii)*NC + c];
        }
        tsp[part*128 + c] = st;
        trsp[part*128 + c] = sd;
    }
    // ---- prefetch W matrix 0 ----
    f16x8 wreg[4];
    #pragma unroll
    for (int it = 0; it < 4; ++it) {
        int s = tid + it*512, c = s >> 4, ks = s & 15;
        wreg[it] = *(const f16x8*)&Wt[c*128 + ks*8];
    }
    __syncthreads();
    #pragma unroll
    for (int it = 0; it < 4; ++it) {
        int s = tid + it*512, c = s >> 4, ks = s & 15;
        *(f16x8*)&WL[c*128 + ((ks ^ (c & 7)) * 8)] = wreg[it];
    }
    if (quarter == 0 && tid < 256) {
        int c = tid & 127;
        float* dst = (tid < 128 ? ts : trs);
        float* src = (tid < 128 ? tsp : trsp);
        dst[c] = (src[c] + src[128+c] + src[256+c] + src[384+c]) / AVGF;
    }

    f32x4 acc3[3];
    acc3[0] = (f32x4)0.f; acc3[1] = (f32x4)0.f; acc3[2] = (f32x4)0.f;
    const int pan[9] = {0,0,0,1,1,2,2,1,2};  // basis 2..10 -> d/r/cl
    const int outp[9] = {2,0,1,0,1,0,1,2,2}; // basis 2..10 -> Dg/A/Bc
    #pragma unroll
    for (int m = 0; m < 9; ++m) {
        __syncthreads();   // WL(m) visible
        if (m < 8) {
            const _Float16* Wn = Wt + (size_t)(m+1) * 16384;
            #pragma unroll
            for (int it = 0; it < 4; ++it) {
                int s = tid + it*512, c = s >> 4, ks = s & 15;
                wreg[it] = *(const f16x8*)&Wn[c*128 + ks*8];
            }
        }
        const _Float16* P = (pan[m] == 0 ? Pd : pan[m] == 1 ? Pr : Pc);
        #pragma unroll
        for (int kt = 0; kt < 4; ++kt) {
            f16x8 a = *(const f16x8*)&P[lr*128 + (((kt*4+lk) ^ (lr & 7)) * 8)];
            f16x8 bb = *(const f16x8*)&WL[col*128 + (((kt*4+lk) ^ (lr & 7)) * 8)];
            MFMA(a, bb, acc3[outp[m]]);
        }
        __syncthreads();   // MFMA reads of WL done
        if (m < 8) {
            #pragma unroll
            for (int it = 0; it < 4; ++it) {
                int s = tid + it*512, c = s >> 4, ks = s & 15;
                *(f16x8*)&WL[c*128 + ((ks ^ (c & 7)) * 8)] = wreg[it];
            }
        }
    }
    #pragma unroll
    for (int q = 0; q < 4; ++q) {
        size_t o = (size_t)(rb + row0 + lk*4 + q) * NC + col;
        A[o]   = acc3[0][q];
        Bc[o]  = acc3[1][q];
        Dgv[o] = acc3[2][q];
    }
    if (quarter == 0) {
        __syncthreads();
        int c = tid & 127, part = tid >> 7;
        float g = 0.f, gd = 0.f;
        for (int k = part*32; k < part*32 + 32; ++k) {
            float tv = ts[k], rv = trs[k];
            g  += tv * Weq[(11*NC + k)*NC + c] + rv * Weq[(13*NC + k)*NC + c];
            gd += tv * Weq[(12*NC + k)*NC + c] + rv * Weq[(14*NC + k)*NC + c];
        }
        tsp[part*128 + c] = g;
        trsp[part*128 + c] = gd;
        __syncthreads();
        if (tid < 128) {
            float gg = eqb[tid] + tsp[tid] + tsp[128+tid] + tsp[256+tid] + tsp[384+tid];
            float gdd = eqbd[tid] + trsp[tid] + trsp[128+tid] + trsp[256+tid] + trsp[384+tid];
            G[b*NC + tid] = gg;
            Gd[b*NC + tid] = gdd;
        }
    }
}

// ---------------- Eq2to0 head + output MLP ----------------
__global__ __launch_bounds__(128) void k_final(
    const float* __restrict__ rsum, const float* __restrict__ diag,
    const float* __restrict__ w20, const float* __restrict__ b20,
    const float* __restrict__ wmlp, const float* __restrict__ bmlp,
    float* __restrict__ outp)
{
    int b = blockIdx.x;
    int c = threadIdx.x;
    __shared__ float agg0[NC], agg1[NC], act3[NC];
    float dgv = 0.f, tot = 0.f;
    for (int i = 0; i < NN; ++i) {
        dgv += diag[(size_t)(b * NN + i) * NC + c];
        tot += rsum[(size_t)(b * NN + i) * NC + c];
    }
    agg0[c] = lrelu(dgv / AVGF);
    agg1[c] = lrelu(tot / AVGF);
    __syncthreads();
    float a3 = b20[c];
    for (int k = 0; k < NC; ++k)
        a3 += agg0[k] * w20[k * NC + c] + agg1[k] * w20[(NC + k) * NC + c];
    act3[c] = a3;
    __syncthreads();
    if (c < 2) {
        float o = bmlp[c];
        for (int d = 0; d < NC; ++d) o += act3[d] * wmlp[d * 2 + c];
        outp[b * 2 + c] = o;
    }
}

extern "C" void kernel_launch(void* const* d_in, const int* in_sizes, int n_in,
                              void* d_out, int out_size, void* d_ws, size_t ws_size,
                              hipStream_t stream)
{
    const float* momenta = (const float*)d_in[0];
    const float* scalars = (const float*)d_in[1];
    const int*   nobj    = (const int*)d_in[2];
    const float* w_lin   = (const float*)d_in[3];
    const float* alpha   = (const float*)d_in[4];
    const float* w_in    = (const float*)d_in[5];
    const float* b_in    = (const float*)d_in[6];
    const float *msgW[4], *msgB[4], *eqW[4], *eqB[4], *eqBd[4];
    const float *wm0, *bm0, *w20, *b20, *wmlp, *bmlp;
    if (n_in >= 33) {
        for (int l = 0; l < 4; ++l) {
            msgW[l] = (const float*)d_in[7 + l];
            msgB[l] = (const float*)d_in[11 + l];
            eqW[l]  = (const float*)d_in[15 + l];
            eqB[l]  = (const float*)d_in[19 + l];
            eqBd[l] = (const float*)d_in[23 + l];
        }
        wm0  = (const float*)d_in[27]; bm0  = (const float*)d_in[28];
        w20  = (const float*)d_in[29]; b20  = (const float*)d_in[30];
        wmlp = (const float*)d_in[31]; bmlp = (const float*)d_in[32];
    } else {
        for (int l = 0; l < 4; ++l) {
            msgW[l] = (const float*)d_in[7] + (size_t)l * NC * NC;
            msgB[l] = (const float*)d_in[8] + l * NC;
            eqW[l]  = (const float*)d_in[9] + (size_t)l * 15 * NC * NC;
            eqB[l]  = (const float*)d_in[10] + l * NC;
            eqBd[l] = (const float*)d_in[11] + l * NC;
        }
        wm0  = (const float*)d_in[12]; bm0  = (const float*)d_in[13];
        w20  = (const float*)d_in[14]; b20  = (const float*)d_in[15];
        wmlp = (const float*)d_in[16]; bmlp = (const float*)d_in[17];
    }

    // ---- workspace layout ----
    const size_t TN2 = (size_t)NB * NN * TILE;       // fp16 elems per tile array
    const size_t RN  = (size_t)NB * NN * NC;         // floats per row-vector array
    _Float16* X  = (_Float16*)d_ws;
    _Float16* Y  = X + TN2;
    _Float16* SW = Y + TN2;                          // 49 * 16384 fp16
    float* fp = (float*)(((uintptr_t)(SW + 49 * 16384) + 15) & ~(uintptr_t)15);
    float* rsum  = fp;
    float* pcsum = rsum + RN;                        // up to 16 chunks
    float* diag  = pcsum + 16 * RN;
    float* Aa    = diag + RN;
    float* Bb    = Aa + RN;
    float* Dgv   = Bb + RN;
    float* G     = Dgv + RN;
    float* Gd    = G + NB * NC;
    float* mask1 = Gd + NB * NC;
    float* P0    = mask1 + NB * NN;
    float* P1    = P0 + (size_t)NB * NN * NCS;
    float* P2    = P1 + (size_t)NB * NN * NCS;
    float* Ps3   = P2 + (size_t)NB * NN * NCS;
    float* Ps4   = Ps3 + NB * NCS;
    size_t need = (size_t)((char*)(Ps4 + NB * NCS) - (char*)d_ws);
    if (ws_size < need) return;

    k_split<<<dim3(64, 49), 256, 0, stream>>>(msgW[0], msgW[1], msgW[2], msgW[3],
                                              wm0, eqW[0], eqW[1], eqW[2], eqW[3], SW);
    k_prep<<<NB, 256, 0, stream>>>(scalars, nobj, w_in, mask1, P0, P1, P2, Ps3, Ps4);

    k_f0<<<512, 512, 0, stream>>>(momenta, mask1, P0, P1, P2, Ps3, Ps4,
                                  b_in, w_lin, alpha, SW /*msgW[0]*/,
                                  msgB[0], X, rsum, diag, pcsum);

    _Float16 *in = X, *out = Y;
    for (int l = 0; l < 4; ++l) {
        _Float16* Wt = SW + (size_t)(13 + l * 9) * 16384;
        k_red3<<<128, 512, 0, stream>>>(rsum, pcsum, diag, Wt, eqW[l],
                                        eqB[l], eqBd[l], (l == 0 ? 16 : 8),
                                        Aa, Bb, Dgv, G, Gd);
        _Float16* W0 = SW + (size_t)(5 + 2 * l) * 16384;
        _Float16* W1 = W0 + 16384;
        if (l < 3) {
            _Float16* Wm = SW + (size_t)(l + 1) * 16384;
            k_feq<1><<<256, 512, 0, stream>>>(in, W0, W1, Wm, msgB[l + 1],
                                              Aa, Bb, Dgv, G, Gd, mask1,
                                              out, rsum, diag, pcsum);
            _Float16* t = in; in = out; out = t;
        } else {
            _Float16* Wm = SW + (size_t)4 * 16384;    // wm0
            k_feq<0><<<256, 512, 0, stream>>>(in, W0, W1, Wm, bm0,
                                              Aa, Bb, Dgv, G, Gd, mask1,
                                              out, rsum, diag, pcsum);
        }
    }
    k_final<<<NB, 128, 0, stream>>>(rsum, diag, w20, b20, wmlp, bmlp, (float*)d_out);
}

// Round 16
// 231.325 us; speedup vs baseline: 2.6908x; 1.0492x over previous
//
#include <hip/hip_runtime.h>
#include <math.h>

#define NB 32
#define NN 64
#define NS 9
#define NCS 32
#define NC 128
#define AVGF 49.0f
#define TILE 8192   // fp16 elems per (b,i) tile: 64 rows x 128 ch

typedef __attribute__((ext_vector_type(8))) _Float16 f16x8;
typedef __attribute__((ext_vector_type(4))) _Float16 f16x4;
typedef __attribute__((ext_vector_type(4))) float f32x4;

#define MFMA(a,bb,c) c = __builtin_amdgcn_mfma_f32_16x16x32_f16(a,bb,c,0,0,0)

__device__ __forceinline__ float lrelu(float x){ return x>0.f ? x : 0.01f*x; }
// swizzled tile element address for (row j, channel c): 16B-slot XOR swizzle
__device__ __forceinline__ int tel(int j,int c){ return j*128 + (((c>>3)^(j&7))<<3) + (c&7); }

// ---------------- convert weights: W[k][c] fp32 -> [c][k] fp16 ----------------
// m 0..4: msgW0..3, wm0 | 5..12: eqW l W0/W1 | 13..48: eqW l basis 2..10
__global__ __launch_bounds__(256) void k_split(
    const float* __restrict__ m0, const float* __restrict__ m1,
    const float* __restrict__ m2, const float* __restrict__ m3,
    const float* __restrict__ m4, const float* __restrict__ e0,
    const float* __restrict__ e1, const float* __restrict__ e2,
    const float* __restrict__ e3, _Float16* __restrict__ outbuf)
{
    int m = blockIdx.y;
    const float* src;
    if (m < 5) src = (m == 0 ? m0 : m == 1 ? m1 : m == 2 ? m2 : m == 3 ? m3 : m4);
    else if (m < 13) {
        int l = (m - 5) >> 1, sub = (m - 5) & 1;
        const float* e = (l == 0 ? e0 : l == 1 ? e1 : l == 2 ? e2 : e3);
        src = e + sub * NC * NC;
    } else {
        int l = (m - 13) / 9, idx = (m - 13) % 9;
        const float* e = (l == 0 ? e0 : l == 1 ? e1 : l == 2 ? e2 : e3);
        src = e + (size_t)(2 + idx) * NC * NC;
    }
    int idx2 = blockIdx.x * 256 + threadIdx.x;
    int k = idx2 >> 7, c = idx2 & 127;
    outbuf[(size_t)m * 16384 + c * NC + k] = (_Float16)src[idx2];
}

// ---------------- prep: mask1, eq1to2 projections ----------------
__global__ __launch_bounds__(256) void k_prep(
    const float* __restrict__ scalars, const int* __restrict__ nobj,
    const float* __restrict__ w_in,
    float* __restrict__ mask1, float* __restrict__ P0,
    float* __restrict__ P1, float* __restrict__ P2,
    float* __restrict__ Ps3, float* __restrict__ Ps4)
{
    int b = blockIdx.x, tid = threadIdx.x;
    __shared__ float xs[NN][NS];
    __shared__ float ss[NS];
    int cnt = nobj[b];
    for (int idx = tid; idx < NN * NS; idx += 256) {
        int i = idx / NS, s = idx - i * NS;
        xs[i][s] = (i < cnt) ? scalars[(b * NN + i) * NS + s] : 0.0f;
    }
    if (tid < NN) mask1[b * NN + tid] = (tid < cnt) ? 1.0f : 0.0f;
    __syncthreads();
    if (tid < NS) {
        float a = 0.f;
        for (int i = 0; i < NN; ++i) a += xs[i][tid];
        ss[tid] = a / AVGF;
    }
    __syncthreads();
    for (int idx = tid; idx < NN * NCS; idx += 256) {
        int i = idx >> 5, d = idx & 31;
        float a0 = 0.f, a1 = 0.f, a2 = 0.f;
        #pragma unroll
        for (int s = 0; s < NS; ++s) {
            float x = xs[i][s];
            a0 += x * w_in[(0 * NS + s) * NCS + d];
            a1 += x * w_in[(1 * NS + s) * NCS + d];
            a2 += x * w_in[(2 * NS + s) * NCS + d];
        }
        P0[(b * NN + i) * NCS + d] = a0;
        P1[(b * NN + i) * NCS + d] = a1;
        P2[(b * NN + i) * NCS + d] = a2;
    }
    if (tid < NCS) {
        float a3 = 0.f, a4 = 0.f;
        #pragma unroll
        for (int s = 0; s < NS; ++s) {
            a3 += ss[s] * w_in[(3 * NS + s) * NCS + tid];
            a4 += ss[s] * w_in[(4 * NS + s) * NCS + tid];
        }
        Ps3[b * NCS + tid] = a3;
        Ps4[b * NCS + tid] = a4;
    }
}

// ---------------- F0 persistent: 8 tiles/block, 2 barriers/tile (no per-tile global deps) ----------------
__global__ __launch_bounds__(512, 2) void k_f0(
    const float* __restrict__ momenta, const float* __restrict__ mask1,
    const float* __restrict__ P0, const float* __restrict__ P1,
    const float* __restrict__ P2, const float* __restrict__ Ps3,
    const float* __restrict__ Ps4, const float* __restrict__ b_in,
    const float* __restrict__ w_lin, const float* __restrict__ alpha,
    const _Float16* __restrict__ Wm, const float* __restrict__ bias,
    _Float16* __restrict__ U, float* __restrict__ rsum, float* __restrict__ diag,
    float* __restrict__ pcsum)
{
    __shared__ __align__(16) char smem[46208];
    _Float16* E   = (_Float16*)smem;                  // [0,16K)
    _Float16* Ust = E + TILE;                         // [16K,32K)
    float* mom  = (float*)(smem + 32768);             // [64][4]
    float* P1s  = mom + 256;                          // [64][32]
    float* psb  = P1s + 2048;                         // [32] Ps3+b_in
    float* wl   = psb + 32;                           // [96]
    float* al   = wl + 96;                            // [96]
    float* mjv  = al + 96;                            // [64]
    float* P0s  = mjv + 64;                           // [8][32] per-tile P0
    float* P2s  = P0s + 256;                          // [8][32] per-tile P2+Ps4
    float* Ls2  = P2s + 256;                          // [2][128]
    int tid = threadIdx.x;
    int wg = blockIdx.x;
    int b = (wg & 7) * 4 + ((wg >> 3) & 3);           // xcd-affine
    int chunk = wg >> 5;                              // 0..7
    int i0 = chunk * 8;
    const int rb = b * NN;
    int w = tid >> 6, l = tid & 63, lr = l & 15, lk = l >> 4;
    int wr = w >> 2, wc = w & 3;
    int c0 = wc * 32 + lr, c1 = c0 + 16;
    // ---- once-per-block staging (everything; no per-tile global loads afterwards) ----
    if (tid < 64) {
        *(float4*)&mom[tid*4] = *(const float4*)&momenta[(size_t)(rb + tid) * 4];
        mjv[tid] = mask1[rb + tid];
    }
    *(float4*)&P1s[tid*4] = *(const float4*)&P1[(size_t)rb * NCS + tid*4];
    if (tid < 32) psb[tid] = Ps3[b*NCS + tid] + b_in[tid];
    if (tid >= 64 && tid < 160) { wl[tid-64] = w_lin[tid-64]; al[tid-64] = alpha[tid-64]; }
    if (tid >= 256 && tid < 512) {
        int s = tid - 256;                            // 0..255 -> [8 tiles][32 ch]
        int ti = s >> 5, c = s & 31;
        P0s[s] = P0[(size_t)(rb + i0 + ti)*NCS + c];
        P2s[s] = P2[(size_t)(rb + i0 + ti)*NCS + c] + Ps4[b*NCS + c];
    }
    // W into registers
    f16x8 wmr[4][2];
    {
        const int cb = c0 * NC + lk * 8;
        #pragma unroll
        for (int kt = 0; kt < 4; ++kt)
            #pragma unroll
            for (int nt = 0; nt < 2; ++nt)
                wmr[kt][nt] = *(const f16x8*)&Wm[cb + nt*16*NC + kt*32];
    }
    float bs0 = bias[c0], bs1 = bias[c1];
    float mjc[2][4];
    float cs0[2][4], cs1[2][4];
    #pragma unroll
    for (int mt = 0; mt < 2; ++mt)
        #pragma unroll
        for (int q = 0; q < 4; ++q) {
            mjc[mt][q] = mask1[rb + (wr*2 + mt)*16 + lk*4 + q];
            cs0[mt][q] = 0.f; cs1[mt][q] = 0.f;
        }
    __syncthreads();   // all block-level staging visible

    int pj = tid >> 4, pks = tid & 15, pc0 = pks * 8;
    for (int t = 0; t < 8; ++t) {
        int i = i0 + t;
        float mi = mjv[i];
        // pi components (LDS broadcast)
        float pi0 = mom[i*4+0], pi1 = mom[i*4+1], pi2 = mom[i*4+2], pi3 = mom[i*4+3];
        // ---- build T0 tile -> E (no barrier needed; inputs staged at block start) ----
        #pragma unroll
        for (int it = 0; it < 2; ++it) {
            int j = pj + it * 32;
            float m2 = mi * mjv[j];
            float v[8];
            if (pks < 4) {
                #pragma unroll
                for (int q = 0; q < 8; ++q) {
                    float x = P0s[t*NCS + pc0+q] + P1s[j*NCS + pc0+q] + psb[pc0+q];
                    if (j == i) x += P2s[t*NCS + pc0+q];
                    v[q] = lrelu(x) * m2;
                }
            } else {
                int c2 = pc0 - NCS;
                float dj = pi0*mom[j*4+0] - pi1*mom[j*4+1] - pi2*mom[j*4+2] - pi3*mom[j*4+3];
                #pragma unroll
                for (int q = 0; q < 8; ++q) {
                    float r = dj * wl[c2+q];
                    float lg = __log2f(1.0f + fabsf(r));
                    float s = al[c2+q] * 0.69314718f * lg;
                    v[q] = __uint_as_float(__float_as_uint(s) ^ (__float_as_uint(r) & 0x80000000u)) * m2;
                }
            }
            f16x8 hv;
            #pragma unroll
            for (int q = 0; q < 8; ++q) hv[q] = (_Float16)v[q];
            *(f16x8*)&E[j*128 + ((pks ^ (j & 7)) * 8)] = hv;
        }
        __syncthreads();   // B1: E ready
        // ---- msg MFMA ----
        f32x4 acc[2][2];
        acc[0][0]=(f32x4)0.f; acc[0][1]=(f32x4)0.f; acc[1][0]=(f32x4)0.f; acc[1][1]=(f32x4)0.f;
        #pragma unroll
        for (int kt = 0; kt < 4; ++kt)
            #pragma unroll
            for (int mt = 0; mt < 2; ++mt) {
                int row = (wr*2 + mt)*16 + lr;
                int slot = ((kt*4 + lk) ^ (row & 7)) * 8;
                f16x8 a = *(const f16x8*)&E[row*128 + slot];
                #pragma unroll
                for (int nt = 0; nt < 2; ++nt)
                    MFMA(a, wmr[kt][nt], acc[mt][nt]);
            }
        // ---- fragment epilogue ----
        float pr0 = 0.f, pr1 = 0.f;
        #pragma unroll
        for (int mt = 0; mt < 2; ++mt)
            #pragma unroll
            for (int q = 0; q < 4; ++q) {
                int j = (wr*2 + mt)*16 + lk*4 + q;
                float m2 = mi * mjc[mt][q];
                float v0 = lrelu(acc[mt][0][q] + bs0) * m2;
                float v1 = lrelu(acc[mt][1][q] + bs1) * m2;
                pr0 += v0; pr1 += v1;
                cs0[mt][q] += v0; cs1[mt][q] += v1;
                if (j == i) {
                    diag[(size_t)(rb+i)*NC + c0] = v0;
                    diag[(size_t)(rb+i)*NC + c1] = v1;
                }
                Ust[tel(j, c0)] = (_Float16)v0;
                Ust[tel(j, c1)] = (_Float16)v1;
            }
        pr0 += __shfl_xor(pr0, 16); pr0 += __shfl_xor(pr0, 32);
        pr1 += __shfl_xor(pr1, 16); pr1 += __shfl_xor(pr1, 32);
        if (l < 16) { Ls2[wr*128 + c0] = pr0; Ls2[wr*128 + c1] = pr1; }
        __syncthreads();   // B2: Ust + Ls2 ready
        size_t t0 = (size_t)(rb + i) * TILE;
        *(f16x8*)&U[t0 + (size_t)tid*8] = *(const f16x8*)&Ust[tid*8];
        *(f16x8*)&U[t0 + (size_t)(tid+512)*8] = *(const f16x8*)&Ust[(tid+512)*8];
        if (tid < 128)
            rsum[(size_t)(rb+i)*NC + tid] = (Ls2[tid] + Ls2[128 + tid]) / AVGF;
    }
    const size_t RN = (size_t)NB * NN * NC;
    #pragma unroll
    for (int mt = 0; mt < 2; ++mt)
        #pragma unroll
        for (int q = 0; q < 4; ++q) {
            int j = (wr*2 + mt)*16 + lk*4 + q;
            pcsum[(size_t)chunk * RN + (size_t)(rb+j)*NC + c0] = cs0[mt][q];
            pcsum[(size_t)chunk * RN + (size_t)(rb+j)*NC + c1] = cs1[mt][q];
        }
}

// ---------------- F_eq persistent: r11-verified — 8 tiles/block, all W in regs, single-buffer ----------------
template<int WOUT>
__global__ __launch_bounds__(512, 2) void k_feq(
    const _Float16* __restrict__ Uin,
    const _Float16* __restrict__ W0, const _Float16* __restrict__ W1,
    const _Float16* __restrict__ Wm, const float* __restrict__ mbias,
    const float* __restrict__ A, const float* __restrict__ Bc,
    const float* __restrict__ Dgv, const float* __restrict__ G,
    const float* __restrict__ Gd, const float* __restrict__ mask1,
    _Float16* __restrict__ Uo, float* __restrict__ rsum, float* __restrict__ diag,
    float* __restrict__ pcsum)
{
    __shared__ __align__(16) char smem[66560];
    _Float16* PA  = (_Float16*)smem;              // [0,16K)
    _Float16* PB  = (_Float16*)(smem + 16384);    // [16K,32K)
    _Float16* E   = (_Float16*)(smem + 32768);    // [32K,48K)
    _Float16* Ust = (_Float16*)(smem + 49152);    // [48K,64K)
    float* Ls2    = (float*)(smem + 65536);       // [2][128]
    int tid = threadIdx.x;
    int wg = blockIdx.x;
    int b = (wg & 7) * 4 + ((wg >> 3) & 3);       // xcd-affine
    int chunk = wg >> 5;                          // 0..7
    int i0 = chunk * 8;
    const int rb = b * NN;
    int w = tid >> 6, l = tid & 63, lr = l & 15, lk = l >> 4;
    int wr = w >> 2, wc = w & 3;
    int c0 = wc * 32 + lr, c1 = c0 + 16;

    // ---- W into registers (once per kernel) ----
    f16x8 w0r[4][2], w1r[4][2], wmr[4][2];
    {
        const int cb = c0 * NC + lk * 8;
        #pragma unroll
        for (int kt = 0; kt < 4; ++kt)
            #pragma unroll
            for (int nt = 0; nt < 2; ++nt) {
                w0r[kt][nt] = *(const f16x8*)&W0[cb + nt*16*NC + kt*32];
                w1r[kt][nt] = *(const f16x8*)&W1[cb + nt*16*NC + kt*32];
                wmr[kt][nt] = *(const f16x8*)&Wm[cb + nt*16*NC + kt*32];
            }
    }
    // ---- i-invariant epilogue constants ----
    float G0 = G[(size_t)b*NC + c0], G1 = G[(size_t)b*NC + c1];
    float Gd0 = Gd[(size_t)b*NC + c0], Gd1 = Gd[(size_t)b*NC + c1];
    float mb0 = mbias[c0], mb1 = mbias[c1];
    float Bv0[2][4], Bv1[2][4], mjc[2][4], cs0[2][4], cs1[2][4];
    #pragma unroll
    for (int mt = 0; mt < 2; ++mt)
        #pragma unroll
        for (int q = 0; q < 4; ++q) {
            int j = (wr*2 + mt)*16 + lk*4 + q;
            Bv0[mt][q] = Bc[(size_t)(rb+j)*NC + c0];
            Bv1[mt][q] = Bc[(size_t)(rb+j)*NC + c1];
            mjc[mt][q] = mask1[rb + j];
            cs0[mt][q] = 0.f; cs1[mt][q] = 0.f;
        }

    int sj = tid >> 4, sks = tid & 15;
    // ---- prologue: stage tile i0 ----
    {
        size_t t0 = (size_t)(rb + i0) * TILE;
        int isw = i0 & 7;
        f16x8 r0 = *(const f16x8*)&Uin[t0 + (size_t)tid*8];
        f16x8 r1 = *(const f16x8*)&Uin[t0 + (size_t)(tid+512)*8];
        f16x8 r2 = *(const f16x8*)&Uin[(size_t)(rb+sj)*TILE + i0*128 + ((sks^isw)*8)];
        f16x8 r3 = *(const f16x8*)&Uin[(size_t)(rb+sj+32)*TILE + i0*128 + ((sks^isw)*8)];
        *(f16x8*)&PA[tid*8] = r0;
        *(f16x8*)&PA[(tid+512)*8] = r1;
        *(f16x8*)&PB[sj*128 + ((sks^(sj&7))*8)] = r2;
        *(f16x8*)&PB[(sj+32)*128 + ((sks^((sj+32)&7))*8)] = r3;
    }
    __syncthreads();

    for (int t = 0; t < 8; ++t) {
        int i = i0 + t;
        float mi = mask1[rb + i];
        float A0v = A[(size_t)(rb+i)*NC + c0] + G0;
        float A1v = A[(size_t)(rb+i)*NC + c1] + G1;
        float D0v = Dgv[(size_t)(rb+i)*NC + c0] + Gd0;
        float D1v = Dgv[(size_t)(rb+i)*NC + c1] + Gd1;
        // issue next-tile staging loads (written into PA/PB after B1)
        f16x8 r0, r1, r2, r3;
        if (t < 7) {
            int in_ = i + 1;
            size_t t0n = (size_t)(rb + in_) * TILE;
            int isw = in_ & 7;
            r0 = *(const f16x8*)&Uin[t0n + (size_t)tid*8];
            r1 = *(const f16x8*)&Uin[t0n + (size_t)(tid+512)*8];
            r2 = *(const f16x8*)&Uin[(size_t)(rb+sj)*TILE + in_*128 + ((sks^isw)*8)];
            r3 = *(const f16x8*)&Uin[(size_t)(rb+sj+32)*TILE + in_*128 + ((sks^isw)*8)];
        }
        // ---- eq MFMA: U@W0 + U^T@W1 ----
        f32x4 acc[2][2];
        acc[0][0]=(f32x4)0.f; acc[0][1]=(f32x4)0.f; acc[1][0]=(f32x4)0.f; acc[1][1]=(f32x4)0.f;
        #pragma unroll
        for (int kt = 0; kt < 4; ++kt)
            #pragma unroll
            for (int mt = 0; mt < 2; ++mt) {
                int row = (wr*2 + mt)*16 + lr;
                int slot = ((kt*4 + lk) ^ (row & 7)) * 8;
                f16x8 a1 = *(const f16x8*)&PA[row*128 + slot];
                f16x8 a2 = *(const f16x8*)&PB[row*128 + slot];
                #pragma unroll
                for (int nt = 0; nt < 2; ++nt) {
                    MFMA(a1, w0r[kt][nt], acc[mt][nt]);
                    MFMA(a2, w1r[kt][nt], acc[mt][nt]);
                }
            }
        // ---- broadcast epilogue -> E ----
        float m2v[2][4];
        #pragma unroll
        for (int mt = 0; mt < 2; ++mt)
            #pragma unroll
            for (int q = 0; q < 4; ++q) {
                int j = (wr*2 + mt)*16 + lk*4 + q;
                float m2 = mi * mjc[mt][q];
                m2v[mt][q] = m2;
                float v0 = acc[mt][0][q] + A0v + Bv0[mt][q];
                float v1 = acc[mt][1][q] + A1v + Bv1[mt][q];
                if (j == i) { v0 += D0v; v1 += D1v; }
                v0 = lrelu(v0) * m2;
                v1 = lrelu(v1) * m2;
                E[tel(j, c0)] = (_Float16)v0;
                E[tel(j, c1)] = (_Float16)v1;
            }
        __syncthreads();   // B1: E ready; ALL PA/PB reads done
        // stage-write next tile's panels (visible to next eq MFMA after B2)
        if (t < 7) {
            *(f16x8*)&PA[tid*8] = r0;
            *(f16x8*)&PA[(tid+512)*8] = r1;
            *(f16x8*)&PB[sj*128 + ((sks^(sj&7))*8)] = r2;
            *(f16x8*)&PB[(sj+32)*128 + ((sks^((sj+32)&7))*8)] = r3;
        }
        // ---- msg MFMA ----
        acc[0][0]=(f32x4)0.f; acc[0][1]=(f32x4)0.f; acc[1][0]=(f32x4)0.f; acc[1][1]=(f32x4)0.f;
        #pragma unroll
        for (int kt = 0; kt < 4; ++kt)
            #pragma unroll
            for (int mt = 0; mt < 2; ++mt) {
                int row = (wr*2 + mt)*16 + lr;
                int slot = ((kt*4 + lk) ^ (row & 7)) * 8;
                f16x8 e = *(const f16x8*)&E[row*128 + slot];
                #pragma unroll
                for (int nt = 0; nt < 2; ++nt)
                    MFMA(e, wmr[kt][nt], acc[mt][nt]);
            }
        // ---- msg epilogue ----
        float pr0 = 0.f, pr1 = 0.f;
        #pragma unroll
        for (int mt = 0; mt < 2; ++mt)
            #pragma unroll
            for (int q = 0; q < 4; ++q) {
                int j = (wr*2 + mt)*16 + lk*4 + q;
                float v0 = lrelu(acc[mt][0][q] + mb0) * m2v[mt][q];
                float v1 = lrelu(acc[mt][1][q] + mb1) * m2v[mt][q];
                pr0 += v0; pr1 += v1;
                if (WOUT) { cs0[mt][q] += v0; cs1[mt][q] += v1; }
                if (j == i) {
                    diag[(size_t)(rb+i)*NC + c0] = v0;
                    diag[(size_t)(rb+i)*NC + c1] = v1;
                }
                if (WOUT) {
                    Ust[tel(j, c0)] = (_Float16)v0;
                    Ust[tel(j, c1)] = (_Float16)v1;
                }
            }
        pr0 += __shfl_xor(pr0, 16); pr0 += __shfl_xor(pr0, 32);
        pr1 += __shfl_xor(pr1, 16); pr1 += __shfl_xor(pr1, 32);
        if (l < 16) { Ls2[wr*128 + c0] = pr0; Ls2[wr*128 + c1] = pr1; }
        __syncthreads();   // B2: Ust + Ls2 ready; PA/PB writes visible
        if (WOUT) {
            size_t t0 = (size_t)(rb + i) * TILE;
            *(f16x8*)&Uo[t0 + (size_t)tid*8] = *(const f16x8*)&Ust[tid*8];
            *(f16x8*)&Uo[t0 + (size_t)(tid+512)*8] = *(const f16x8*)&Ust[(tid+512)*8];
        }
        if (tid < 128)
            rsum[(size_t)(rb+i)*NC + tid] = (Ls2[tid] + Ls2[128 + tid]) / AVGF;
    }
    if (WOUT) {
        const size_t RN = (size_t)NB * NN * NC;
        #pragma unroll
        for (int mt = 0; mt < 2; ++mt)
            #pragma unroll
            for (int q = 0; q < 4; ++q) {
                int j = (wr*2 + mt)*16 + lk*4 + q;
                pcsum[(size_t)chunk * RN + (size_t)(rb+j)*NC + c0] = cs0[mt][q];
                pcsum[(size_t)chunk * RN + (size_t)(rb+j)*NC + c1] = cs1[mt][q];
            }
    }
}

// ---------------- red3 via MFMA: 128 blocks = 32b x 4 row-quarters ----------------
__global__ __launch_bounds__(512, 2) void k_red3(
    const float* __restrict__ rsum, const float* __restrict__ pcsum,
    const float* __restrict__ diag, const _Float16* __restrict__ Wt,
    const float* __restrict__ Weq, const float* __restrict__ eqb,
    const float* __restrict__ eqbd,
    float* __restrict__ A, float* __restrict__ Bc, float* __restrict__ Dgv,
    float* __restrict__ G, float* __restrict__ Gd)
{
    __shared__ __align__(16) char smem[50176];
    _Float16* Pd = (_Float16*)smem;            // [16][128] tel layout
    _Float16* Pr = Pd + 2048;
    _Float16* Pc = Pr + 2048;
    _Float16* WL = Pc + 2048;                  // [128][128] swizzled, 32KB
    float* tsp  = (float*)(smem + 45056);      // [4][128]
    float* trsp = tsp + 512;                   // [4][128]
    float* ts   = trsp + 512;                  // [128]
    float* trs  = ts + 128;                    // [128]
    int tid = threadIdx.x;
    int wg = blockIdx.x;
    int b = (wg & 7) * 4 + ((wg >> 3) & 3);    // xcd-affine
    int quarter = wg >> 5;
    int row0 = quarter * 16;
    const int rb = b * NN;
    const size_t RN = (size_t)NB * NN * NC;
    int w = tid >> 6, l = tid & 63, lr = l & 15, lk = l >> 4;
    int col = w * 16 + lr;                     // wave w owns 16 cols

    // ---- stage d/r panels ----
    {
        int s = tid & 255, prow = s >> 4, pks = s & 15;
        const float* src = (tid < 256 ? diag : rsum) + (size_t)(rb + row0 + prow) * NC + pks * 8;
        float4 f0 = *(const float4*)src, f1 = *(const float4*)(src + 4);
        float vv[8] = {f0.x,f0.y,f0.z,f0.w,f1.x,f1.y,f1.z,f1.w};
        f16x8 hv;
        #pragma unroll
        for (int q = 0; q < 8; ++q) hv[q] = (_Float16)vv[q];
        _Float16* dst = (tid < 256 ? Pd : Pr);
        *(f16x8*)&dst[prow*128 + ((pks ^ (prow & 7)) * 8)] = hv;
    }
    // ---- stage cl panel (sum 8 chunks) ----
    {
        int prow = tid >> 5, kq = tid & 31;
        size_t o = (size_t)(rb + row0 + prow) * NC + kq * 4;
        float s0 = 0, s1 = 0, s2 = 0, s3 = 0;
        #pragma unroll
        for (int ch = 0; ch < 8; ++ch) {
            float4 v = *(const float4*)&pcsum[(size_t)ch * RN + o];
            s0 += v.x; s1 += v.y; s2 += v.z; s3 += v.w;
        }
        f16x4 hv;
        hv[0] = (_Float16)(s0 / AVGF); hv[1] = (_Float16)(s1 / AVGF);
        hv[2] = (_Float16)(s2 / AVGF); hv[3] = (_Float16)(s3 / AVGF);
        *(f16x4*)&Pc[prow*128 + (((kq >> 1) ^ (prow & 7)) << 3) + (kq & 1) * 4] = hv;
    }
    // ---- quarter-0: ts/trs partials ----
    if (quarter == 0) {
        int c = tid & 127, part = tid >> 7;
        float st = 0.f, sd = 0.f;
        for (int ii = part*16; ii < part*16 + 16; ++ii) {
            st += rsum[(size_t)(rb+ii)*NC + c];
            sd += diag[(size_t)(rb+ii)*NC + c];
        }
        tsp[part*128 + c] = st;
        trsp[part*128 + c] = sd;
    }
    // ---- prefetch W matrix 0 ----
    f16x8 wreg[4];
    #pragma unroll
    for (int it = 0; it < 4; ++it) {
        int s = tid + it*512, c = s >> 4, ks = s & 15;
        wreg[it] = *(const f16x8*)&Wt[c*128 + ks*8];
    }
    __syncthreads();
    #pragma unroll
    for (int it = 0; it < 4; ++it) {
        int s = tid + it*512, c = s >> 4, ks = s & 15;
        *(f16x8*)&WL[c*128 + ((ks ^ (c & 7)) * 8)] = wreg[it];
    }
    if (quarter == 0 && tid < 256) {
        int c = tid & 127;
        float* dst = (tid < 128 ? ts : trs);
        float* src = (tid < 128 ? tsp : trsp);
        dst[c] = (src[c] + src[128+c] + src[256+c] + src[384+c]) / AVGF;
    }

    f32x4 acc3[3];
    acc3[0] = (f32x4)0.f; acc3[1] = (f32x4)0.f; acc3[2] = (f32x4)0.f;
    const int pan[9] = {0,0,0,1,1,2,2,1,2};  // basis 2..10 -> d/r/cl
    const int outp[9] = {2,0,1,0,1,0,1,2,2}; // basis 2..10 -> Dg/A/Bc
    #pragma unroll
    for (int m = 0; m < 9; ++m) {
        __syncthreads();   // WL(m) visible
        if (m < 8) {
            const _Float16* Wn = Wt + (size_t)(m+1) * 16384;
            #pragma unroll
            for (int it = 0; it < 4; ++it) {
                int s = tid + it*512, c = s >> 4, ks = s & 15;
                wreg[it] = *(const f16x8*)&Wn[c*128 + ks*8];
            }
        }
        const _Float16* P = (pan[m] == 0 ? Pd : pan[m] == 1 ? Pr : Pc);
        #pragma unroll
        for (int kt = 0; kt < 4; ++kt) {
            f16x8 a = *(const f16x8*)&P[lr*128 + (((kt*4+lk) ^ (lr & 7)) * 8)];
            f16x8 bb = *(const f16x8*)&WL[col*128 + (((kt*4+lk) ^ (lr & 7)) * 8)];
            MFMA(a, bb, acc3[outp[m]]);
        }
        __syncthreads();   // MFMA reads of WL done
        if (m < 8) {
            #pragma unroll
            for (int it = 0; it < 4; ++it) {
                int s = tid + it*512, c = s >> 4, ks = s & 15;
                *(f16x8*)&WL[c*128 + ((ks ^ (c & 7)) * 8)] = wreg[it];
            }
        }
    }
    #pragma unroll
    for (int q = 0; q < 4; ++q) {
        size_t o = (size_t)(rb + row0 + lk*4 + q) * NC + col;
        A[o]   = acc3[0][q];
        Bc[o]  = acc3[1][q];
        Dgv[o] = acc3[2][q];
    }
    if (quarter == 0) {
        __syncthreads();
        int c = tid & 127, part = tid >> 7;
        float g = 0.f, gd = 0.f;
        for (int k = part*32; k < part*32 + 32; ++k) {
            float tv = ts[k], rv = trs[k];
            g  += tv * Weq[(11*NC + k)*NC + c] + rv * Weq[(13*NC + k)*NC + c];
            gd += tv * Weq[(12*NC + k)*NC + c] + rv * Weq[(14*NC + k)*NC + c];
        }
        tsp[part*128 + c] = g;
        trsp[part*128 + c] = gd;
        __syncthreads();
        if (tid < 128) {
            float gg = eqb[tid] + tsp[tid] + tsp[128+tid] + tsp[256+tid] + tsp[384+tid];
            float gdd = eqbd[tid] + trsp[tid] + trsp[128+tid] + trsp[256+tid] + trsp[384+tid];
            G[b*NC + tid] = gg;
            Gd[b*NC + tid] = gdd;
        }
    }
}

// ---------------- Eq2to0 head + output MLP ----------------
__global__ __launch_bounds__(128) void k_final(
    const float* __restrict__ rsum, const float* __restrict__ diag,
    const float* __restrict__ w20, const float* __restrict__ b20,
    const float* __restrict__ wmlp, const float* __restrict__ bmlp,
    float* __restrict__ outp)
{
    int b = blockIdx.x;
    int c = threadIdx.x;
    __shared__ float agg0[NC], agg1[NC], act3[NC];
    float dgv = 0.f, tot = 0.f;
    for (int i = 0; i < NN; ++i) {
        dgv += diag[(size_t)(b * NN + i) * NC + c];
        tot += rsum[(size_t)(b * NN + i) * NC + c];
    }
    agg0[c] = lrelu(dgv / AVGF);
    agg1[c] = lrelu(tot / AVGF);
    __syncthreads();
    float a3 = b20[c];
    for (int k = 0; k < NC; ++k)
        a3 += agg0[k] * w20[k * NC + c] + agg1[k] * w20[(NC + k) * NC + c];
    act3[c] = a3;
    __syncthreads();
    if (c < 2) {
        float o = bmlp[c];
        for (int d = 0; d < NC; ++d) o += act3[d] * wmlp[d * 2 + c];
        outp[b * 2 + c] = o;
    }
}

extern "C" void kernel_launch(void* const* d_in, const int* in_sizes, int n_in,
                              void* d_out, int out_size, void* d_ws, size_t ws_size,
                              hipStream_t stream)
{
    const float* momenta = (const float*)d_in[0];
    const float* scalars = (const float*)d_in[1];
    const int*   nobj    = (const int*)d_in[2];
    const float* w_lin   = (const float*)d_in[3];
    const float* alpha   = (const float*)d_in[4];
    const float* w_in    = (const float*)d_in[5];
    const float* b_in    = (const float*)d_in[6];
    const float *msgW[4], *msgB[4], *eqW[4], *eqB[4], *eqBd[4];
    const float *wm0, *bm0, *w20, *b20, *wmlp, *bmlp;
    if (n_in >= 33) {
        for (int l = 0; l < 4; ++l) {
            msgW[l] = (const float*)d_in[7 + l];
            msgB[l] = (const float*)d_in[11 + l];
            eqW[l]  = (const float*)d_in[15 + l];
            eqB[l]  = (const float*)d_in[19 + l];
            eqBd[l] = (const float*)d_in[23 + l];
        }
        wm0  = (const float*)d_in[27]; bm0  = (const float*)d_in[28];
        w20  = (const float*)d_in[29]; b20  = (const float*)d_in[30];
        wmlp = (const float*)d_in[31]; bmlp = (const float*)d_in[32];
    } else {
        for (int l = 0; l < 4; ++l) {
            msgW[l] = (const float*)d_in[7] + (size_t)l * NC * NC;
            msgB[l] = (const float*)d_in[8] + l * NC;
            eqW[l]  = (const float*)d_in[9] + (size_t)l * 15 * NC * NC;
            eqB[l]  = (const float*)d_in[10] + l * NC;
            eqBd[l] = (const float*)d_in[11] + l * NC;
        }
        wm0  = (const float*)d_in[12]; bm0  = (const float*)d_in[13];
        w20  = (const float*)d_in[14]; b20  = (const float*)d_in[15];
        wmlp = (const float*)d_in[16]; bmlp = (const float*)d_in[17];
    }

    // ---- workspace layout ----
    const size_t TN2 = (size_t)NB * NN * TILE;       // fp16 elems per tile array
    const size_t RN  = (size_t)NB * NN * NC;         // floats per row-vector array
    _Float16* X  = (_Float16*)d_ws;
    _Float16* Y  = X + TN2;
    _Float16* SW = Y + TN2;                          // 49 * 16384 fp16
    float* fp = (float*)(((uintptr_t)(SW + 49 * 16384) + 15) & ~(uintptr_t)15);
    float* rsum  = fp;
    float* pcsum = rsum + RN;                        // 8 chunks
    float* diag  = pcsum + 8 * RN;
    float* Aa    = diag + RN;
    float* Bb    = Aa + RN;
    float* Dgv   = Bb + RN;
    float* G     = Dgv + RN;
    float* Gd    = G + NB * NC;
    float* mask1 = Gd + NB * NC;
    float* P0    = mask1 + NB * NN;
    float* P1    = P0 + (size_t)NB * NN * NCS;
    float* P2    = P1 + (size_t)NB * NN * NCS;
    float* Ps3   = P2 + (size_t)NB * NN * NCS;
    float* Ps4   = Ps3 + NB * NCS;
    size_t need = (size_t)((char*)(Ps4 + NB * NCS) - (char*)d_ws);
    if (ws_size < need) return;

    k_split<<<dim3(64, 49), 256, 0, stream>>>(msgW[0], msgW[1], msgW[2], msgW[3],
                                              wm0, eqW[0], eqW[1], eqW[2], eqW[3], SW);
    k_prep<<<NB, 256, 0, stream>>>(scalars, nobj, w_in, mask1, P0, P1, P2, Ps3, Ps4);

    k_f0<<<256, 512, 0, stream>>>(momenta, mask1, P0, P1, P2, Ps3, Ps4,
                                  b_in, w_lin, alpha, SW /*msgW[0]*/,
                                  msgB[0], X, rsum, diag, pcsum);

    _Float16 *in = X, *out = Y;
    for (int l = 0; l < 4; ++l) {
        _Float16* Wt = SW + (size_t)(13 + l * 9) * 16384;
        k_red3<<<128, 512, 0, stream>>>(rsum, pcsum, diag, Wt, eqW[l],
                                        eqB[l], eqBd[l], Aa, Bb, Dgv, G, Gd);
        _Float16* W0 = SW + (size_t)(5 + 2 * l) * 16384;
        _Float16* W1 = W0 + 16384;
        if (l < 3) {
            _Float16* Wm = SW + (size_t)(l + 1) * 16384;
            k_feq<1><<<256, 512, 0, stream>>>(in, W0, W1, Wm, msgB[l + 1],
                                              Aa, Bb, Dgv, G, Gd, mask1,
                                              out, rsum, diag, pcsum);
            _Float16* t = in; in = out; out = t;
        } else {
            _Float16* Wm = SW + (size_t)4 * 16384;    // wm0
            k_feq<0><<<256, 512, 0, stream>>>(in, W0, W1, Wm, bm0,
                                              Aa, Bb, Dgv, G, Gd, mask1,
                                              out, rsum, diag, pcsum);
        }
    }
    k_final<<<NB, 128, 0, stream>>>(rsum, diag, w20, b20, wmlp, bmlp, (float*)d_out);
}

// Round 17
// 228.488 us; speedup vs baseline: 2.7242x; 1.0124x over previous
//
#include <hip/hip_runtime.h>
#include <math.h>

#define NB 32
#define NN 64
#define NS 9
#define NCS 32
#define NC 128
#define AVGF 49.0f
#define TILE 8192   // fp16 elems per (b,i) tile: 64 rows x 128 ch

typedef __attribute__((ext_vector_type(8))) _Float16 f16x8;
typedef __attribute__((ext_vector_type(4))) _Float16 f16x4;
typedef __attribute__((ext_vector_type(4))) float f32x4;

#define MFMA(a,bb,c) c = __builtin_amdgcn_mfma_f32_16x16x32_f16(a,bb,c,0,0,0)

__device__ __forceinline__ float lrelu(float x){ return x>0.f ? x : 0.01f*x; }
// swizzled tile element address for (row j, channel c): 16B-slot XOR swizzle
__device__ __forceinline__ int tel(int j,int c){ return j*128 + (((c>>3)^(j&7))<<3) + (c&7); }

// ---------------- k_init: fused weight-convert (blocks 0..3135) + prep (last 32 blocks) ----------------
// split: m 0..4: msgW0..3, wm0 | 5..12: eqW l W0/W1 | 13..48: eqW l basis 2..10
__global__ __launch_bounds__(256) void k_init(
    const float* __restrict__ m0, const float* __restrict__ m1,
    const float* __restrict__ m2, const float* __restrict__ m3,
    const float* __restrict__ m4, const float* __restrict__ e0,
    const float* __restrict__ e1, const float* __restrict__ e2,
    const float* __restrict__ e3, _Float16* __restrict__ outbuf,
    const float* __restrict__ scalars, const int* __restrict__ nobj,
    const float* __restrict__ w_in,
    float* __restrict__ mask1, float* __restrict__ P0,
    float* __restrict__ P1, float* __restrict__ P2,
    float* __restrict__ Ps3, float* __restrict__ Ps4)
{
    int bid = blockIdx.x, tid = threadIdx.x;
    if (bid < 49 * 64) {
        // ---- weight convert branch ----
        int m = bid >> 6;
        const float* src;
        if (m < 5) src = (m == 0 ? m0 : m == 1 ? m1 : m == 2 ? m2 : m == 3 ? m3 : m4);
        else if (m < 13) {
            int l = (m - 5) >> 1, sub = (m - 5) & 1;
            const float* e = (l == 0 ? e0 : l == 1 ? e1 : l == 2 ? e2 : e3);
            src = e + sub * NC * NC;
        } else {
            int l = (m - 13) / 9, idx = (m - 13) % 9;
            const float* e = (l == 0 ? e0 : l == 1 ? e1 : l == 2 ? e2 : e3);
            src = e + (size_t)(2 + idx) * NC * NC;
        }
        int idx2 = (bid & 63) * 256 + tid;
        int k = idx2 >> 7, c = idx2 & 127;
        outbuf[(size_t)m * 16384 + c * NC + k] = (_Float16)src[idx2];
        return;
    }
    // ---- prep branch (block-uniform, syncthreads safe) ----
    int b = bid - 49 * 64;
    __shared__ float xs[NN][NS];
    __shared__ float ss[NS];
    int cnt = nobj[b];
    for (int idx = tid; idx < NN * NS; idx += 256) {
        int i = idx / NS, s = idx - i * NS;
        xs[i][s] = (i < cnt) ? scalars[(b * NN + i) * NS + s] : 0.0f;
    }
    if (tid < NN) mask1[b * NN + tid] = (tid < cnt) ? 1.0f : 0.0f;
    __syncthreads();
    if (tid < NS) {
        float a = 0.f;
        for (int i = 0; i < NN; ++i) a += xs[i][tid];
        ss[tid] = a / AVGF;
    }
    __syncthreads();
    for (int idx = tid; idx < NN * NCS; idx += 256) {
        int i = idx >> 5, d = idx & 31;
        float a0 = 0.f, a1 = 0.f, a2 = 0.f;
        #pragma unroll
        for (int s = 0; s < NS; ++s) {
            float x = xs[i][s];
            a0 += x * w_in[(0 * NS + s) * NCS + d];
            a1 += x * w_in[(1 * NS + s) * NCS + d];
            a2 += x * w_in[(2 * NS + s) * NCS + d];
        }
        P0[(b * NN + i) * NCS + d] = a0;
        P1[(b * NN + i) * NCS + d] = a1;
        P2[(b * NN + i) * NCS + d] = a2;
    }
    if (tid < NCS) {
        float a3 = 0.f, a4 = 0.f;
        #pragma unroll
        for (int s = 0; s < NS; ++s) {
            a3 += ss[s] * w_in[(3 * NS + s) * NCS + tid];
            a4 += ss[s] * w_in[(4 * NS + s) * NCS + tid];
        }
        Ps3[b * NCS + tid] = a3;
        Ps4[b * NCS + tid] = a4;
    }
}

// ---------------- F0 persistent: 8 tiles/block, 2 barriers/tile (no per-tile global deps) ----------------
__global__ __launch_bounds__(512, 2) void k_f0(
    const float* __restrict__ momenta, const float* __restrict__ mask1,
    const float* __restrict__ P0, const float* __restrict__ P1,
    const float* __restrict__ P2, const float* __restrict__ Ps3,
    const float* __restrict__ Ps4, const float* __restrict__ b_in,
    const float* __restrict__ w_lin, const float* __restrict__ alpha,
    const _Float16* __restrict__ Wm, const float* __restrict__ bias,
    _Float16* __restrict__ U, float* __restrict__ rsum, float* __restrict__ diag,
    float* __restrict__ pcsum)
{
    __shared__ __align__(16) char smem[46208];
    _Float16* E   = (_Float16*)smem;                  // [0,16K)
    _Float16* Ust = E + TILE;                         // [16K,32K)
    float* mom  = (float*)(smem + 32768);             // [64][4]
    float* P1s  = mom + 256;                          // [64][32]
    float* psb  = P1s + 2048;                         // [32] Ps3+b_in
    float* wl   = psb + 32;                           // [96]
    float* al   = wl + 96;                            // [96]
    float* mjv  = al + 96;                            // [64]
    float* P0s  = mjv + 64;                           // [8][32] per-tile P0
    float* P2s  = P0s + 256;                          // [8][32] per-tile P2+Ps4
    float* Ls2  = P2s + 256;                          // [2][128]
    int tid = threadIdx.x;
    int wg = blockIdx.x;
    int b = (wg & 7) * 4 + ((wg >> 3) & 3);           // xcd-affine
    int chunk = wg >> 5;                              // 0..7
    int i0 = chunk * 8;
    const int rb = b * NN;
    int w = tid >> 6, l = tid & 63, lr = l & 15, lk = l >> 4;
    int wr = w >> 2, wc = w & 3;
    int c0 = wc * 32 + lr, c1 = c0 + 16;
    // ---- once-per-block staging (everything; no per-tile global loads afterwards) ----
    if (tid < 64) {
        *(float4*)&mom[tid*4] = *(const float4*)&momenta[(size_t)(rb + tid) * 4];
        mjv[tid] = mask1[rb + tid];
    }
    *(float4*)&P1s[tid*4] = *(const float4*)&P1[(size_t)rb * NCS + tid*4];
    if (tid < 32) psb[tid] = Ps3[b*NCS + tid] + b_in[tid];
    if (tid >= 64 && tid < 160) { wl[tid-64] = w_lin[tid-64]; al[tid-64] = alpha[tid-64]; }
    if (tid >= 256 && tid < 512) {
        int s = tid - 256;                            // 0..255 -> [8 tiles][32 ch]
        int ti = s >> 5, c = s & 31;
        P0s[s] = P0[(size_t)(rb + i0 + ti)*NCS + c];
        P2s[s] = P2[(size_t)(rb + i0 + ti)*NCS + c] + Ps4[b*NCS + c];
    }
    // W into registers
    f16x8 wmr[4][2];
    {
        const int cb = c0 * NC + lk * 8;
        #pragma unroll
        for (int kt = 0; kt < 4; ++kt)
            #pragma unroll
            for (int nt = 0; nt < 2; ++nt)
                wmr[kt][nt] = *(const f16x8*)&Wm[cb + nt*16*NC + kt*32];
    }
    float bs0 = bias[c0], bs1 = bias[c1];
    float mjc[2][4];
    float cs0[2][4], cs1[2][4];
    #pragma unroll
    for (int mt = 0; mt < 2; ++mt)
        #pragma unroll
        for (int q = 0; q < 4; ++q) {
            mjc[mt][q] = mask1[rb + (wr*2 + mt)*16 + lk*4 + q];
            cs0[mt][q] = 0.f; cs1[mt][q] = 0.f;
        }
    __syncthreads();   // all block-level staging visible

    int pj = tid >> 4, pks = tid & 15, pc0 = pks * 8;
    for (int t = 0; t < 8; ++t) {
        int i = i0 + t;
        float mi = mjv[i];
        float pi0 = mom[i*4+0], pi1 = mom[i*4+1], pi2 = mom[i*4+2], pi3 = mom[i*4+3];
        // ---- build T0 tile -> E ----
        #pragma unroll
        for (int it = 0; it < 2; ++it) {
            int j = pj + it * 32;
            float m2 = mi * mjv[j];
            float v[8];
            if (pks < 4) {
                #pragma unroll
                for (int q = 0; q < 8; ++q) {
                    float x = P0s[t*NCS + pc0+q] + P1s[j*NCS + pc0+q] + psb[pc0+q];
                    if (j == i) x += P2s[t*NCS + pc0+q];
                    v[q] = lrelu(x) * m2;
                }
            } else {
                int c2 = pc0 - NCS;
                float dj = pi0*mom[j*4+0] - pi1*mom[j*4+1] - pi2*mom[j*4+2] - pi3*mom[j*4+3];
                #pragma unroll
                for (int q = 0; q < 8; ++q) {
                    float r = dj * wl[c2+q];
                    float lg = __log2f(1.0f + fabsf(r));
                    float s = al[c2+q] * 0.69314718f * lg;
                    v[q] = __uint_as_float(__float_as_uint(s) ^ (__float_as_uint(r) & 0x80000000u)) * m2;
                }
            }
            f16x8 hv;
            #pragma unroll
            for (int q = 0; q < 8; ++q) hv[q] = (_Float16)v[q];
            *(f16x8*)&E[j*128 + ((pks ^ (j & 7)) * 8)] = hv;
        }
        __syncthreads();   // B1: E ready
        // ---- msg MFMA ----
        f32x4 acc[2][2];
        acc[0][0]=(f32x4)0.f; acc[0][1]=(f32x4)0.f; acc[1][0]=(f32x4)0.f; acc[1][1]=(f32x4)0.f;
        #pragma unroll
        for (int kt = 0; kt < 4; ++kt)
            #pragma unroll
            for (int mt = 0; mt < 2; ++mt) {
                int row = (wr*2 + mt)*16 + lr;
                int slot = ((kt*4 + lk) ^ (row & 7)) * 8;
                f16x8 a = *(const f16x8*)&E[row*128 + slot];
                #pragma unroll
                for (int nt = 0; nt < 2; ++nt)
                    MFMA(a, wmr[kt][nt], acc[mt][nt]);
            }
        // ---- fragment epilogue ----
        float pr0 = 0.f, pr1 = 0.f;
        #pragma unroll
        for (int mt = 0; mt < 2; ++mt)
            #pragma unroll
            for (int q = 0; q < 4; ++q) {
                int j = (wr*2 + mt)*16 + lk*4 + q;
                float m2 = mi * mjc[mt][q];
                float v0 = lrelu(acc[mt][0][q] + bs0) * m2;
                float v1 = lrelu(acc[mt][1][q] + bs1) * m2;
                pr0 += v0; pr1 += v1;
                cs0[mt][q] += v0; cs1[mt][q] += v1;
                if (j == i) {
                    diag[(size_t)(rb+i)*NC + c0] = v0;
                    diag[(size_t)(rb+i)*NC + c1] = v1;
                }
                Ust[tel(j, c0)] = (_Float16)v0;
                Ust[tel(j, c1)] = (_Float16)v1;
            }
        pr0 += __shfl_xor(pr0, 16); pr0 += __shfl_xor(pr0, 32);
        pr1 += __shfl_xor(pr1, 16); pr1 += __shfl_xor(pr1, 32);
        if (l < 16) { Ls2[wr*128 + c0] = pr0; Ls2[wr*128 + c1] = pr1; }
        __syncthreads();   // B2: Ust + Ls2 ready
        size_t t0 = (size_t)(rb + i) * TILE;
        *(f16x8*)&U[t0 + (size_t)tid*8] = *(const f16x8*)&Ust[tid*8];
        *(f16x8*)&U[t0 + (size_t)(tid+512)*8] = *(const f16x8*)&Ust[(tid+512)*8];
        if (tid < 128)
            rsum[(size_t)(rb+i)*NC + tid] = (Ls2[tid] + Ls2[128 + tid]) / AVGF;
    }
    const size_t RN = (size_t)NB * NN * NC;
    #pragma unroll
    for (int mt = 0; mt < 2; ++mt)
        #pragma unroll
        for (int q = 0; q < 4; ++q) {
            int j = (wr*2 + mt)*16 + lk*4 + q;
            pcsum[(size_t)chunk * RN + (size_t)(rb+j)*NC + c0] = cs0[mt][q];
            pcsum[(size_t)chunk * RN + (size_t)(rb+j)*NC + c1] = cs1[mt][q];
        }
}

// ---------------- F_eq persistent: 8 tiles/block, all W in regs, single-buffer ----------------
template<int WOUT>
__global__ __launch_bounds__(512, 2) void k_feq(
    const _Float16* __restrict__ Uin,
    const _Float16* __restrict__ W0, const _Float16* __restrict__ W1,
    const _Float16* __restrict__ Wm, const float* __restrict__ mbias,
    const float* __restrict__ A, const float* __restrict__ Bc,
    const float* __restrict__ Dgv, const float* __restrict__ G,
    const float* __restrict__ Gd, const float* __restrict__ mask1,
    _Float16* __restrict__ Uo, float* __restrict__ rsum, float* __restrict__ diag,
    float* __restrict__ pcsum)
{
    __shared__ __align__(16) char smem[66560];
    _Float16* PA  = (_Float16*)smem;              // [0,16K)
    _Float16* PB  = (_Float16*)(smem + 16384);    // [16K,32K)
    _Float16* E   = (_Float16*)(smem + 32768);    // [32K,48K)
    _Float16* Ust = (_Float16*)(smem + 49152);    // [48K,64K)
    float* Ls2    = (float*)(smem + 65536);       // [2][128]
    int tid = threadIdx.x;
    int wg = blockIdx.x;
    int b = (wg & 7) * 4 + ((wg >> 3) & 3);       // xcd-affine
    int chunk = wg >> 5;                          // 0..7
    int i0 = chunk * 8;
    const int rb = b * NN;
    int w = tid >> 6, l = tid & 63, lr = l & 15, lk = l >> 4;
    int wr = w >> 2, wc = w & 3;
    int c0 = wc * 32 + lr, c1 = c0 + 16;

    // ---- W into registers (once per kernel) ----
    f16x8 w0r[4][2], w1r[4][2], wmr[4][2];
    {
        const int cb = c0 * NC + lk * 8;
        #pragma unroll
        for (int kt = 0; kt < 4; ++kt)
            #pragma unroll
            for (int nt = 0; nt < 2; ++nt) {
                w0r[kt][nt] = *(const f16x8*)&W0[cb + nt*16*NC + kt*32];
                w1r[kt][nt] = *(const f16x8*)&W1[cb + nt*16*NC + kt*32];
                wmr[kt][nt] = *(const f16x8*)&Wm[cb + nt*16*NC + kt*32];
            }
    }
    // ---- i-invariant epilogue constants ----
    float G0 = G[(size_t)b*NC + c0], G1 = G[(size_t)b*NC + c1];
    float Gd0 = Gd[(size_t)b*NC + c0], Gd1 = Gd[(size_t)b*NC + c1];
    float mb0 = mbias[c0], mb1 = mbias[c1];
    float Bv0[2][4], Bv1[2][4], mjc[2][4], cs0[2][4], cs1[2][4];
    #pragma unroll
    for (int mt = 0; mt < 2; ++mt)
        #pragma unroll
        for (int q = 0; q < 4; ++q) {
            int j = (wr*2 + mt)*16 + lk*4 + q;
            Bv0[mt][q] = Bc[(size_t)(rb+j)*NC + c0];
            Bv1[mt][q] = Bc[(size_t)(rb+j)*NC + c1];
            mjc[mt][q] = mask1[rb + j];
            cs0[mt][q] = 0.f; cs1[mt][q] = 0.f;
        }

    int sj = tid >> 4, sks = tid & 15;
    // ---- prologue: stage tile i0 ----
    {
        size_t t0 = (size_t)(rb + i0) * TILE;
        int isw = i0 & 7;
        f16x8 r0 = *(const f16x8*)&Uin[t0 + (size_t)tid*8];
        f16x8 r1 = *(const f16x8*)&Uin[t0 + (size_t)(tid+512)*8];
        f16x8 r2 = *(const f16x8*)&Uin[(size_t)(rb+sj)*TILE + i0*128 + ((sks^isw)*8)];
        f16x8 r3 = *(const f16x8*)&Uin[(size_t)(rb+sj+32)*TILE + i0*128 + ((sks^isw)*8)];
        *(f16x8*)&PA[tid*8] = r0;
        *(f16x8*)&PA[(tid+512)*8] = r1;
        *(f16x8*)&PB[sj*128 + ((sks^(sj&7))*8)] = r2;
        *(f16x8*)&PB[(sj+32)*128 + ((sks^((sj+32)&7))*8)] = r3;
    }
    __syncthreads();

    for (int t = 0; t < 8; ++t) {
        int i = i0 + t;
        float mi = mask1[rb + i];
        float A0v = A[(size_t)(rb+i)*NC + c0] + G0;
        float A1v = A[(size_t)(rb+i)*NC + c1] + G1;
        float D0v = Dgv[(size_t)(rb+i)*NC + c0] + Gd0;
        float D1v = Dgv[(size_t)(rb+i)*NC + c1] + Gd1;
        // issue next-tile staging loads (written into PA/PB after B1)
        f16x8 r0, r1, r2, r3;
        if (t < 7) {
            int in_ = i + 1;
            size_t t0n = (size_t)(rb + in_) * TILE;
            int isw = in_ & 7;
            r0 = *(const f16x8*)&Uin[t0n + (size_t)tid*8];
            r1 = *(const f16x8*)&Uin[t0n + (size_t)(tid+512)*8];
            r2 = *(const f16x8*)&Uin[(size_t)(rb+sj)*TILE + in_*128 + ((sks^isw)*8)];
            r3 = *(const f16x8*)&Uin[(size_t)(rb+sj+32)*TILE + in_*128 + ((sks^isw)*8)];
        }
        // ---- eq MFMA: U@W0 + U^T@W1 ----
        f32x4 acc[2][2];
        acc[0][0]=(f32x4)0.f; acc[0][1]=(f32x4)0.f; acc[1][0]=(f32x4)0.f; acc[1][1]=(f32x4)0.f;
        #pragma unroll
        for (int kt = 0; kt < 4; ++kt)
            #pragma unroll
            for (int mt = 0; mt < 2; ++mt) {
                int row = (wr*2 + mt)*16 + lr;
                int slot = ((kt*4 + lk) ^ (row & 7)) * 8;
                f16x8 a1 = *(const f16x8*)&PA[row*128 + slot];
                f16x8 a2 = *(const f16x8*)&PB[row*128 + slot];
                #pragma unroll
                for (int nt = 0; nt < 2; ++nt) {
                    MFMA(a1, w0r[kt][nt], acc[mt][nt]);
                    MFMA(a2, w1r[kt][nt], acc[mt][nt]);
                }
            }
        // ---- broadcast epilogue -> E ----
        float m2v[2][4];
        #pragma unroll
        for (int mt = 0; mt < 2; ++mt)
            #pragma unroll
            for (int q = 0; q < 4; ++q) {
                int j = (wr*2 + mt)*16 + lk*4 + q;
                float m2 = mi * mjc[mt][q];
                m2v[mt][q] = m2;
                float v0 = acc[mt][0][q] + A0v + Bv0[mt][q];
                float v1 = acc[mt][1][q] + A1v + Bv1[mt][q];
                if (j == i) { v0 += D0v; v1 += D1v; }
                v0 = lrelu(v0) * m2;
                v1 = lrelu(v1) * m2;
                E[tel(j, c0)] = (_Float16)v0;
                E[tel(j, c1)] = (_Float16)v1;
            }
        __syncthreads();   // B1: E ready; ALL PA/PB reads done
        // stage-write next tile's panels (visible to next eq MFMA after B2)
        if (t < 7) {
            *(f16x8*)&PA[tid*8] = r0;
            *(f16x8*)&PA[(tid+512)*8] = r1;
            *(f16x8*)&PB[sj*128 + ((sks^(sj&7))*8)] = r2;
            *(f16x8*)&PB[(sj+32)*128 + ((sks^((sj+32)&7))*8)] = r3;
        }
        // ---- msg MFMA ----
        acc[0][0]=(f32x4)0.f; acc[0][1]=(f32x4)0.f; acc[1][0]=(f32x4)0.f; acc[1][1]=(f32x4)0.f;
        #pragma unroll
        for (int kt = 0; kt < 4; ++kt)
            #pragma unroll
            for (int mt = 0; mt < 2; ++mt) {
                int row = (wr*2 + mt)*16 + lr;
                int slot = ((kt*4 + lk) ^ (row & 7)) * 8;
                f16x8 e = *(const f16x8*)&E[row*128 + slot];
                #pragma unroll
                for (int nt = 0; nt < 2; ++nt)
                    MFMA(e, wmr[kt][nt], acc[mt][nt]);
            }
        // ---- msg epilogue ----
        float pr0 = 0.f, pr1 = 0.f;
        #pragma unroll
        for (int mt = 0; mt < 2; ++mt)
            #pragma unroll
            for (int q = 0; q < 4; ++q) {
                int j = (wr*2 + mt)*16 + lk*4 + q;
                float v0 = lrelu(acc[mt][0][q] + mb0) * m2v[mt][q];
                float v1 = lrelu(acc[mt][1][q] + mb1) * m2v[mt][q];
                pr0 += v0; pr1 += v1;
                if (WOUT) { cs0[mt][q] += v0; cs1[mt][q] += v1; }
                if (j == i) {
                    diag[(size_t)(rb+i)*NC + c0] = v0;
                    diag[(size_t)(rb+i)*NC + c1] = v1;
                }
                if (WOUT) {
                    Ust[tel(j, c0)] = (_Float16)v0;
                    Ust[tel(j, c1)] = (_Float16)v1;
                }
            }
        pr0 += __shfl_xor(pr0, 16); pr0 += __shfl_xor(pr0, 32);
        pr1 += __shfl_xor(pr1, 16); pr1 += __shfl_xor(pr1, 32);
        if (l < 16) { Ls2[wr*128 + c0] = pr0; Ls2[wr*128 + c1] = pr1; }
        __syncthreads();   // B2: Ust + Ls2 ready; PA/PB writes visible
        if (WOUT) {
            size_t t0 = (size_t)(rb + i) * TILE;
            *(f16x8*)&Uo[t0 + (size_t)tid*8] = *(const f16x8*)&Ust[tid*8];
            *(f16x8*)&Uo[t0 + (size_t)(tid+512)*8] = *(const f16x8*)&Ust[(tid+512)*8];
        }
        if (tid < 128)
            rsum[(size_t)(rb+i)*NC + tid] = (Ls2[tid] + Ls2[128 + tid]) / AVGF;
    }
    if (WOUT) {
        const size_t RN = (size_t)NB * NN * NC;
        #pragma unroll
        for (int mt = 0; mt < 2; ++mt)
            #pragma unroll
            for (int q = 0; q < 4; ++q) {
                int j = (wr*2 + mt)*16 + lk*4 + q;
                pcsum[(size_t)chunk * RN + (size_t)(rb+j)*NC + c0] = cs0[mt][q];
                pcsum[(size_t)chunk * RN + (size_t)(rb+j)*NC + c1] = cs1[mt][q];
            }
    }
}

// ---------------- red3 via MFMA: 128 blocks = 32b x 4 row-quarters ----------------
__global__ __launch_bounds__(512, 2) void k_red3(
    const float* __restrict__ rsum, const float* __restrict__ pcsum,
    const float* __restrict__ diag, const _Float16* __restrict__ Wt,
    const float* __restrict__ Weq, const float* __restrict__ eqb,
    const float* __restrict__ eqbd,
    float* __restrict__ A, float* __restrict__ Bc, float* __restrict__ Dgv,
    float* __restrict__ G, float* __restrict__ Gd)
{
    __shared__ __align__(16) char smem[50176];
    _Float16* Pd = (_Float16*)smem;            // [16][128] tel layout
    _Float16* Pr = Pd + 2048;
    _Float16* Pc = Pr + 2048;
    _Float16* WL = Pc + 2048;                  // [128][128] swizzled, 32KB
    float* tsp  = (float*)(smem + 45056);      // [4][128]
    float* trsp = tsp + 512;                   // [4][128]
    float* ts   = trsp + 512;                  // [128]
    float* trs  = ts + 128;                    // [128]
    int tid = threadIdx.x;
    int wg = blockIdx.x;
    int b = (wg & 7) * 4 + ((wg >> 3) & 3);    // xcd-affine
    int quarter = wg >> 5;
    int row0 = quarter * 16;
    const int rb = b * NN;
    const size_t RN = (size_t)NB * NN * NC;
    int w = tid >> 6, l = tid & 63, lr = l & 15, lk = l >> 4;
    int col = w * 16 + lr;                     // wave w owns 16 cols

    // ---- stage d/r panels ----
    {
        int s = tid & 255, prow = s >> 4, pks = s & 15;
        const float* src = (tid < 256 ? diag : rsum) + (size_t)(rb + row0 + prow) * NC + pks * 8;
        float4 f0 = *(const float4*)src, f1 = *(const float4*)(src + 4);
        float vv[8] = {f0.x,f0.y,f0.z,f0.w,f1.x,f1.y,f1.z,f1.w};
        f16x8 hv;
        #pragma unroll
        for (int q = 0; q < 8; ++q) hv[q] = (_Float16)vv[q];
        _Float16* dst = (tid < 256 ? Pd : Pr);
        *(f16x8*)&dst[prow*128 + ((pks ^ (prow & 7)) * 8)] = hv;
    }
    // ---- stage cl panel (sum 8 chunks) ----
    {
        int prow = tid >> 5, kq = tid & 31;
        size_t o = (size_t)(rb + row0 + prow) * NC + kq * 4;
        float s0 = 0, s1 = 0, s2 = 0, s3 = 0;
        #pragma unroll
        for (int ch = 0; ch < 8; ++ch) {
            float4 v = *(const float4*)&pcsum[(size_t)ch * RN + o];
            s0 += v.x; s1 += v.y; s2 += v.z; s3 += v.w;
        }
        f16x4 hv;
        hv[0] = (_Float16)(s0 / AVGF); hv[1] = (_Float16)(s1 / AVGF);
        hv[2] = (_Float16)(s2 / AVGF); hv[3] = (_Float16)(s3 / AVGF);
        *(f16x4*)&Pc[prow*128 + (((kq >> 1) ^ (prow & 7)) << 3) + (kq & 1) * 4] = hv;
    }
    // ---- quarter-0: ts/trs partials ----
    if (quarter == 0) {
        int c = tid & 127, part = tid >> 7;
        float st = 0.f, sd = 0.f;
        for (int ii = part*16; ii < part*16 + 16; ++ii) {
            st += rsum[(size_t)(rb+ii)*NC + c];
            sd += diag[(size_t)(rb+ii)*NC + c];
        }
        tsp[part*128 + c] = st;
        trsp[part*128 + c] = sd;
    }
    // ---- prefetch W matrix 0 ----
    f16x8 wreg[4];
    #pragma unroll
    for (int it = 0; it < 4; ++it) {
        int s = tid + it*512, c = s >> 4, ks = s & 15;
        wreg[it] = *(const f16x8*)&Wt[c*128 + ks*8];
    }
    __syncthreads();
    #pragma unroll
    for (int it = 0; it < 4; ++it) {
        int s = tid + it*512, c = s >> 4, ks = s & 15;
        *(f16x8*)&WL[c*128 + ((ks ^ (c & 7)) * 8)] = wreg[it];
    }
    if (quarter == 0 && tid < 256) {
        int c = tid & 127;
        float* dst = (tid < 128 ? ts : trs);
        float* src = (tid < 128 ? tsp : trsp);
        dst[c] = (src[c] + src[128+c] + src[256+c] + src[384+c]) / AVGF;
    }

    f32x4 acc3[3];
    acc3[0] = (f32x4)0.f; acc3[1] = (f32x4)0.f; acc3[2] = (f32x4)0.f;
    const int pan[9] = {0,0,0,1,1,2,2,1,2};  // basis 2..10 -> d/r/cl
    const int outp[9] = {2,0,1,0,1,0,1,2,2}; // basis 2..10 -> Dg/A/Bc
    #pragma unroll
    for (int m = 0; m < 9; ++m) {
        __syncthreads();   // WL(m) visible
        if (m < 8) {
            const _Float16* Wn = Wt + (size_t)(m+1) * 16384;
            #pragma unroll
            for (int it = 0; it < 4; ++it) {
                int s = tid + it*512, c = s >> 4, ks = s & 15;
                wreg[it] = *(const f16x8*)&Wn[c*128 + ks*8];
            }
        }
        const _Float16* P = (pan[m] == 0 ? Pd : pan[m] == 1 ? Pr : Pc);
        #pragma unroll
        for (int kt = 0; kt < 4; ++kt) {
            f16x8 a = *(const f16x8*)&P[lr*128 + (((kt*4+lk) ^ (lr & 7)) * 8)];
            f16x8 bb = *(const f16x8*)&WL[col*128 + (((kt*4+lk) ^ (lr & 7)) * 8)];
            MFMA(a, bb, acc3[outp[m]]);
        }
        __syncthreads();   // MFMA reads of WL done
        if (m < 8) {
            #pragma unroll
            for (int it = 0; it < 4; ++it) {
                int s = tid + it*512, c = s >> 4, ks = s & 15;
                *(f16x8*)&WL[c*128 + ((ks ^ (c & 7)) * 8)] = wreg[it];
            }
        }
    }
    #pragma unroll
    for (int q = 0; q < 4; ++q) {
        size_t o = (size_t)(rb + row0 + lk*4 + q) * NC + col;
        A[o]   = acc3[0][q];
        Bc[o]  = acc3[1][q];
        Dgv[o] = acc3[2][q];
    }
    if (quarter == 0) {
        __syncthreads();
        int c = tid & 127, part = tid >> 7;
        float g = 0.f, gd = 0.f;
        for (int k = part*32; k < part*32 + 32; ++k) {
            float tv = ts[k], rv = trs[k];
            g  += tv * Weq[(11*NC + k)*NC + c] + rv * Weq[(13*NC + k)*NC + c];
            gd += tv * Weq[(12*NC + k)*NC + c] + rv * Weq[(14*NC + k)*NC + c];
        }
        tsp[part*128 + c] = g;
        trsp[part*128 + c] = gd;
        __syncthreads();
        if (tid < 128) {
            float gg = eqb[tid] + tsp[tid] + tsp[128+tid] + tsp[256+tid] + tsp[384+tid];
            float gdd = eqbd[tid] + trsp[tid] + trsp[128+tid] + trsp[256+tid] + trsp[384+tid];
            G[b*NC + tid] = gg;
            Gd[b*NC + tid] = gdd;
        }
    }
}

// ---------------- Eq2to0 head + output MLP ----------------
__global__ __launch_bounds__(128) void k_final(
    const float* __restrict__ rsum, const float* __restrict__ diag,
    const float* __restrict__ w20, const float* __restrict__ b20,
    const float* __restrict__ wmlp, const float* __restrict__ bmlp,
    float* __restrict__ outp)
{
    int b = blockIdx.x;
    int c = threadIdx.x;
    __shared__ float agg0[NC], agg1[NC], act3[NC];
    float dgv = 0.f, tot = 0.f;
    for (int i = 0; i < NN; ++i) {
        dgv += diag[(size_t)(b * NN + i) * NC + c];
        tot += rsum[(size_t)(b * NN + i) * NC + c];
    }
    agg0[c] = lrelu(dgv / AVGF);
    agg1[c] = lrelu(tot / AVGF);
    __syncthreads();
    float a3 = b20[c];
    for (int k = 0; k < NC; ++k)
        a3 += agg0[k] * w20[k * NC + c] + agg1[k] * w20[(NC + k) * NC + c];
    act3[c] = a3;
    __syncthreads();
    if (c < 2) {
        float o = bmlp[c];
        for (int d = 0; d < NC; ++d) o += act3[d] * wmlp[d * 2 + c];
        outp[b * 2 + c] = o;
    }
}

extern "C" void kernel_launch(void* const* d_in, const int* in_sizes, int n_in,
                              void* d_out, int out_size, void* d_ws, size_t ws_size,
                              hipStream_t stream)
{
    const float* momenta = (const float*)d_in[0];
    const float* scalars = (const float*)d_in[1];
    const int*   nobj    = (const int*)d_in[2];
    const float* w_lin   = (const float*)d_in[3];
    const float* alpha   = (const float*)d_in[4];
    const float* w_in    = (const float*)d_in[5];
    const float* b_in    = (const float*)d_in[6];
    const float *msgW[4], *msgB[4], *eqW[4], *eqB[4], *eqBd[4];
    const float *wm0, *bm0, *w20, *b20, *wmlp, *bmlp;
    if (n_in >= 33) {
        for (int l = 0; l < 4; ++l) {
            msgW[l] = (const float*)d_in[7 + l];
            msgB[l] = (const float*)d_in[11 + l];
            eqW[l]  = (const float*)d_in[15 + l];
            eqB[l]  = (const float*)d_in[19 + l];
            eqBd[l] = (const float*)d_in[23 + l];
        }
        wm0  = (const float*)d_in[27]; bm0  = (const float*)d_in[28];
        w20  = (const float*)d_in[29]; b20  = (const float*)d_in[30];
        wmlp = (const float*)d_in[31]; bmlp = (const float*)d_in[32];
    } else {
        for (int l = 0; l < 4; ++l) {
            msgW[l] = (const float*)d_in[7] + (size_t)l * NC * NC;
            msgB[l] = (const float*)d_in[8] + l * NC;
            eqW[l]  = (const float*)d_in[9] + (size_t)l * 15 * NC * NC;
            eqB[l]  = (const float*)d_in[10] + l * NC;
            eqBd[l] = (const float*)d_in[11] + l * NC;
        }
        wm0  = (const float*)d_in[12]; bm0  = (const float*)d_in[13];
        w20  = (const float*)d_in[14]; b20  = (const float*)d_in[15];
        wmlp = (const float*)d_in[16]; bmlp = (const float*)d_in[17];
    }

    // ---- workspace layout ----
    const size_t TN2 = (size_t)NB * NN * TILE;       // fp16 elems per tile array
    const size_t RN  = (size_t)NB * NN * NC;         // floats per row-vector array
    _Float16* X  = (_Float16*)d_ws;
    _Float16* Y  = X + TN2;
    _Float16* SW = Y + TN2;                          // 49 * 16384 fp16
    float* fp = (float*)(((uintptr_t)(SW + 49 * 16384) + 15) & ~(uintptr_t)15);
    float* rsum  = fp;
    float* pcsum = rsum + RN;                        // 8 chunks
    float* diag  = pcsum + 8 * RN;
    float* Aa    = diag + RN;
    float* Bb    = Aa + RN;
    float* Dgv   = Bb + RN;
    float* G     = Dgv + RN;
    float* Gd    = G + NB * NC;
    float* mask1 = Gd + NB * NC;
    float* P0    = mask1 + NB * NN;
    float* P1    = P0 + (size_t)NB * NN * NCS;
    float* P2    = P1 + (size_t)NB * NN * NCS;
    float* Ps3   = P2 + (size_t)NB * NN * NCS;
    float* Ps4   = Ps3 + NB * NCS;
    size_t need = (size_t)((char*)(Ps4 + NB * NCS) - (char*)d_ws);
    if (ws_size < need) return;

    k_init<<<49 * 64 + NB, 256, 0, stream>>>(msgW[0], msgW[1], msgW[2], msgW[3],
                                             wm0, eqW[0], eqW[1], eqW[2], eqW[3], SW,
                                             scalars, nobj, w_in, mask1,
                                             P0, P1, P2, Ps3, Ps4);

    k_f0<<<256, 512, 0, stream>>>(momenta, mask1, P0, P1, P2, Ps3, Ps4,
                                  b_in, w_lin, alpha, SW /*msgW[0]*/,
                                  msgB[0], X, rsum, diag, pcsum);

    _Float16 *in = X, *out = Y;
    for (int l = 0; l < 4; ++l) {
        _Float16* Wt = SW + (size_t)(13 + l * 9) * 16384;
        k_red3<<<128, 512, 0, stream>>>(rsum, pcsum, diag, Wt, eqW[l],
                                        eqB[l], eqBd[l], Aa, Bb, Dgv, G, Gd);
        _Float16* W0 = SW + (size_t)(5 + 2 * l) * 16384;
        _Float16* W1 = W0 + 16384;
        if (l < 3) {
            _Float16* Wm = SW + (size_t)(l + 1) * 16384;
            k_feq<1><<<256, 512, 0, stream>>>(in, W0, W1, Wm, msgB[l + 1],
                                              Aa, Bb, Dgv, G, Gd, mask1,
                                              out, rsum, diag, pcsum);
            _Float16* t = in; in = out; out = t;
        } else {
            _Float16* Wm = SW + (size_t)4 * 16384;    // wm0
            k_feq<0><<<256, 512, 0, stream>>>(in, W0, W1, Wm, bm0,
                                              Aa, Bb, Dgv, G, Gd, mask1,
                                              out, rsum, diag, pcsum);
        }
    }
    k_final<<<NB, 128, 0, stream>>>(rsum, diag, w20, b20, wmlp, bmlp, (float*)d_out);
}